// Round 6
// baseline (783.502 us; speedup 1.0000x reference)
//
#include <hip/hip_runtime.h>
#include <hip/hip_bf16.h>
#include <hip/hip_cooperative_groups.h>

namespace cg = cooperative_groups;

#define NNODES 50000
#define NEDGES 600000
#define NGRAPHS 512
#define BN_EPS 1e-5f

typedef short bf16x8 __attribute__((ext_vector_type(8)));
typedef float f32x4 __attribute__((ext_vector_type(4)));

// split fp32 -> hi/lo bf16 (RNE); hi+lo carries ~16 mantissa bits (weights only)
__device__ __forceinline__ void bf_split(float x, ushort& h, ushort& l) {
    __hip_bfloat16 bh = __float2bfloat16(x);
    float r = x - __bfloat162float(bh);
    __hip_bfloat16 bl = __float2bfloat16(r);
    h = __builtin_bit_cast(ushort, bh);
    l = __builtin_bit_cast(ushort, bl);
}
__device__ __forceinline__ ushort f2b(float x) {
    return __builtin_bit_cast(ushort, __float2bfloat16(x));
}
__device__ __forceinline__ float b2f(ushort u) {
    union { uint i; float f; } c; c.i = ((uint)u) << 16; return c.f;
}
// bf16 pair unpack from a packed uint: lo = shift, hi = mask (1 VALU each)
__device__ __forceinline__ float blo(uint u) {
    union { uint i; float f; } c; c.i = u << 16; return c.f;
}
__device__ __forceinline__ float bhi(uint u) {
    union { uint i; float f; } c; c.i = u & 0xffff0000u; return c.f;
}

// ------------------------------------------------------------------ setup
// ONE cooperative dispatch replacing {memset(counts), prep, scan1, scan3,
// scatter}: phase0 zero counts + x->bf16 + zero pooled + wsplit (frag
// order) -> sync -> hist -> sync -> chunk sums -> sync -> scan (exact
// scan3 logic) -> sync -> scatter. Per-element numerics identical to the
// split-dispatch version. Grid 1024 blocks (4/CU, co-residency safe).
__global__ __launch_bounds__(256, 4) void setup_kernel(
    const float* __restrict__ x, ushort* __restrict__ xh,
    float* __restrict__ pooled,
    const int* __restrict__ src, const int* __restrict__ dst,
    int* __restrict__ counts, int* __restrict__ cursor,
    int* __restrict__ row_ptr, int* __restrict__ esrc,
    int* __restrict__ partials,
    const float* W0, const float* W1, const float* W2,
    const float* W3, const float* W4, const float* W5,
    ushort* __restrict__ hi, ushort* __restrict__ lo) {
    cg::grid_group grid = cg::this_grid();
    const int t = threadIdx.x;
    const int tid = blockIdx.x * 256 + t;
    const int nth = gridDim.x * 256;

    // ---------------- phase 0: zeroing + conversions (all independent)
    for (int i = tid; i < NNODES; i += nth) counts[i] = 0;
    if (tid == 0) row_ptr[NNODES] = NEDGES;
    for (int i = tid; i < 800000; i += nth) {       // x: 6.4M floats -> bf16
        int f4 = i * 2;
        float4 a0 = ((const float4*)x)[f4];
        float4 a1 = ((const float4*)x)[f4 + 1];
        ushort4 u0 = {f2b(a0.x), f2b(a0.y), f2b(a0.z), f2b(a0.w)};
        ushort4 u1 = {f2b(a1.x), f2b(a1.y), f2b(a1.z), f2b(a1.w)};
        int e0 = f4 * 4;
        *(ushort4*)(xh + e0) = u0;
        *(ushort4*)(xh + e0 + 4) = u1;
    }
    for (int i = tid; i < NGRAPHS * 96; i += nth)   // pooled: 512*384 floats
        ((float4*)pooled)[i] = make_float4(0.f, 0.f, 0.f, 0.f);
    {
        const float* Ws[6] = {W0, W1, W2, W3, W4, W5};
        for (int i = tid; i < 6 * 16384; i += nth) { // wsplit, frag order
            int mat = i >> 14, idx = i & 16383;
            int j    = idx & 7;
            int lane = (idx >> 3) & 63;
            int nt2  = (idx >> 9) & 7;
            int kb   = (idx >> 12) & 3;
            int k = kb * 32 + ((lane >> 4) << 3) + j;
            int n = nt2 * 16 + (lane & 15);
            ushort hh, ll;
            bf_split(Ws[mat][k * 128 + n], hh, ll);
            hi[(size_t)mat * 16384 + idx] = hh;
            lo[(size_t)mat * 16384 + idx] = ll;
        }
    }
    grid.sync();
    // ---------------- phase 1: hist
    for (int i = tid; i < NEDGES; i += nth) atomicAdd(&counts[dst[i]], 1);
    grid.sync();
    // ---------------- phase 2a: per-256-chunk sums (blocks 0..195)
    __shared__ int s[256];
    __shared__ int base_sh;
    const int nb = (NNODES + 255) / 256;            // 196
    if ((int)blockIdx.x < nb) {
        int i = blockIdx.x * 256 + t;
        int v = (i < NNODES) ? counts[i] : 0;
        s[t] = v;
        __syncthreads();
        for (int off = 128; off > 0; off >>= 1) {
            if (t < off) s[t] += s[t + off];
            __syncthreads();
        }
        if (t == 0) partials[blockIdx.x] = s[0];
    }
    grid.sync();
    // ---------------- phase 2b: exclusive scan (exact scan3 logic)
    if ((int)blockIdx.x < nb) {
        int pv = (t < (int)blockIdx.x && t < nb) ? partials[t] : 0;
        s[t] = pv;
        __syncthreads();
        for (int off = 128; off > 0; off >>= 1) {
            if (t < off) s[t] += s[t + off];
            __syncthreads();
        }
        if (t == 0) base_sh = s[0];
        __syncthreads();
        int base = base_sh;
        int i = blockIdx.x * 256 + t;
        int v = (i < NNODES) ? counts[i] : 0;
        __syncthreads();
        s[t] = v;
        __syncthreads();
        for (int off = 1; off < 256; off <<= 1) {
            int nv = (t >= off) ? s[t - off] : 0;
            __syncthreads();
            s[t] += nv;
            __syncthreads();
        }
        if (i < NNODES) {
            int ex = base + s[t] - v;   // exclusive
            row_ptr[i] = ex;
            cursor[i] = ex;
        }
    }
    grid.sync();
    // ---------------- phase 3: scatter
    for (int i = tid; i < NEDGES; i += nth) {
        int p = atomicAdd(&cursor[dst[i]], 1);
        esrc[p] = src[i];
    }
}

// ------------------------------------------------------------- aggregation
// R4-proven: 4 nodes/wave, 16 lanes x 8 ch (uint4 = 16B/lane). Per-channel
// 8/2/1 pairwise-tree accumulation -> bitwise-identical output across
// layout variants. Fabric-floor-bound (~35us/layer, R4/R5 probes).
__global__ __launch_bounds__(256) void agg_kernel(
    const ushort* __restrict__ phi,
    const int* __restrict__ rp, const int* __restrict__ esrc,
    ushort* __restrict__ ohi, int n) {
    int wid  = (blockIdx.x * 256 + threadIdx.x) >> 6;
    int lane = threadIdx.x & 63;
    int node = wid * 4 + (lane >> 4);
    int q = lane & 15;                   // 16B granule: channels q*8..q*8+7
    if (node >= n) return;
    const uint4* xv = (const uint4*)phi; // row = 16 granules of 16B
    uint4 s0 = xv[(size_t)node * 16 + q];
    float acc[8];
    acc[0] = blo(s0.x); acc[1] = bhi(s0.x);
    acc[2] = blo(s0.y); acc[3] = bhi(s0.y);
    acc[4] = blo(s0.z); acc[5] = bhi(s0.z);
    acc[6] = blo(s0.w); acc[7] = bhi(s0.w);
    int e = rp[node], end = rp[node + 1];
    for (; e + 8 <= end; e += 8) {
        int i0 = esrc[e],     i1 = esrc[e + 1], i2 = esrc[e + 2], i3 = esrc[e + 3];
        int i4 = esrc[e + 4], i5 = esrc[e + 5], i6 = esrc[e + 6], i7 = esrc[e + 7];
        uint4 v0 = xv[(size_t)i0 * 16 + q];
        uint4 v1 = xv[(size_t)i1 * 16 + q];
        uint4 v2 = xv[(size_t)i2 * 16 + q];
        uint4 v3 = xv[(size_t)i3 * 16 + q];
        uint4 v4 = xv[(size_t)i4 * 16 + q];
        uint4 v5 = xv[(size_t)i5 * 16 + q];
        uint4 v6 = xv[(size_t)i6 * 16 + q];
        uint4 v7 = xv[(size_t)i7 * 16 + q];
        acc[0] += ((blo(v0.x) + blo(v1.x)) + (blo(v2.x) + blo(v3.x))) +
                  ((blo(v4.x) + blo(v5.x)) + (blo(v6.x) + blo(v7.x)));
        acc[1] += ((bhi(v0.x) + bhi(v1.x)) + (bhi(v2.x) + bhi(v3.x))) +
                  ((bhi(v4.x) + bhi(v5.x)) + (bhi(v6.x) + bhi(v7.x)));
        acc[2] += ((blo(v0.y) + blo(v1.y)) + (blo(v2.y) + blo(v3.y))) +
                  ((blo(v4.y) + blo(v5.y)) + (blo(v6.y) + blo(v7.y)));
        acc[3] += ((bhi(v0.y) + bhi(v1.y)) + (bhi(v2.y) + bhi(v3.y))) +
                  ((bhi(v4.y) + bhi(v5.y)) + (bhi(v6.y) + bhi(v7.y)));
        acc[4] += ((blo(v0.z) + blo(v1.z)) + (blo(v2.z) + blo(v3.z))) +
                  ((blo(v4.z) + blo(v5.z)) + (blo(v6.z) + blo(v7.z)));
        acc[5] += ((bhi(v0.z) + bhi(v1.z)) + (bhi(v2.z) + bhi(v3.z))) +
                  ((bhi(v4.z) + bhi(v5.z)) + (bhi(v6.z) + bhi(v7.z)));
        acc[6] += ((blo(v0.w) + blo(v1.w)) + (blo(v2.w) + blo(v3.w))) +
                  ((blo(v4.w) + blo(v5.w)) + (blo(v6.w) + blo(v7.w)));
        acc[7] += ((bhi(v0.w) + bhi(v1.w)) + (bhi(v2.w) + bhi(v3.w))) +
                  ((bhi(v4.w) + bhi(v5.w)) + (bhi(v6.w) + bhi(v7.w)));
    }
    for (; e + 2 <= end; e += 2) {
        int i0 = esrc[e], i1 = esrc[e + 1];
        uint4 v0 = xv[(size_t)i0 * 16 + q];
        uint4 v1 = xv[(size_t)i1 * 16 + q];
        acc[0] += blo(v0.x) + blo(v1.x); acc[1] += bhi(v0.x) + bhi(v1.x);
        acc[2] += blo(v0.y) + blo(v1.y); acc[3] += bhi(v0.y) + bhi(v1.y);
        acc[4] += blo(v0.z) + blo(v1.z); acc[5] += bhi(v0.z) + bhi(v1.z);
        acc[6] += blo(v0.w) + blo(v1.w); acc[7] += bhi(v0.w) + bhi(v1.w);
    }
    for (; e < end; e++) {
        uint4 v = xv[(size_t)esrc[e] * 16 + q];
        acc[0] += blo(v.x); acc[1] += bhi(v.x);
        acc[2] += blo(v.y); acc[3] += bhi(v.y);
        acc[4] += blo(v.z); acc[5] += bhi(v.z);
        acc[6] += blo(v.w); acc[7] += bhi(v.w);
    }
    uint4 o;
    o.x = (uint)f2b(acc[0]) | ((uint)f2b(acc[1]) << 16);
    o.y = (uint)f2b(acc[2]) | ((uint)f2b(acc[3]) << 16);
    o.z = (uint)f2b(acc[4]) | ((uint)f2b(acc[5]) << 16);
    o.w = (uint)f2b(acc[6]) | ((uint)f2b(acc[7]) << 16);
    *(uint4*)(ohi + (size_t)node * 128 + q * 8) = o;
}

// --------------------------------------------------------------- fused MLP
// C = act( BN_ReLU( A@W1 ) @ W2 ), 64-row tile x 128 threads (2 waves).
// PER-WAVE SHAPE UNCHANGED from proven R14: 64x64 wave tile, 4x4 frags,
// 32 MFMA/kb. W planes stored in MFMA-fragment order -> each bh/bl load is
// one coalesced contiguous 1KB wave transaction. Fused mean-pool epilogue.
template <bool RELU_OUT, bool WRITE_PLANES>
__global__ __launch_bounds__(128) void mlp_kernel(
    const ushort* __restrict__ Ah,
    const ushort* __restrict__ W1hi, const ushort* __restrict__ W1lo,
    const ushort* __restrict__ W2hi, const ushort* __restrict__ W2lo,
    const float* __restrict__ b1, const float* __restrict__ gm,
    const float* __restrict__ bt, const float* __restrict__ rm,
    const float* __restrict__ rv, const float* __restrict__ b2,
    ushort* __restrict__ Ch,
    const int* __restrict__ batch, float* __restrict__ pooled, int poff, int M) {
    __shared__ __align__(16) ushort smem[64 * 136];   // 17408 B
    __shared__ int bsm[64];
    // A dbuf: smem[buf*4096 + m*32 + k]  (8192 ushorts, fits in smem)
    // H / P:  smem[row*136 + col]
    const int t = threadIdx.x;            // 0..127
    const int lane = t & 63;
    const int wv = t >> 6;                // col half
    const int row0 = blockIdx.x * 64;
    const int g = lane >> 4, c = lane & 15;

    if (t < 64) bsm[t] = (row0 + t < M) ? batch[row0 + t] : -1;

    // staging: 256 16B-segs per kb; thread owns segs t and t+128
    const int m0 = t >> 2, k80 = (t & 3) * 8;
    const int m1 = m0 + 32;
    int r0 = row0 + m0; if (r0 >= M) r0 = M - 1;
    int r1 = row0 + m1; if (r1 >= M) r1 = M - 1;
    const size_t ga0 = (size_t)r0 * 128 + k80;
    const size_t ga1 = (size_t)r1 * 128 + k80;
    const int la0 = m0 * 32 + k80, la1 = m1 * 32 + k80;

    f32x4 acc[4][4];
#pragma unroll
    for (int i = 0; i < 4; i++)
#pragma unroll
        for (int j = 0; j < 4; j++) acc[i][j] = (f32x4){0.f, 0.f, 0.f, 0.f};

    uint4 ph0 = *(const uint4*)(Ah + ga0);
    uint4 ph1 = *(const uint4*)(Ah + ga1);
    *(uint4*)&smem[la0] = ph0;
    *(uint4*)&smem[la1] = ph1;
    __syncthreads();

    // ---------------- phase 1: A @ W1 (2 terms)
    int cur = 0;
    for (int kb = 0; kb < 4; kb++) {
        bf16x8 bh[4], bl[4];
#pragma unroll
        for (int ct = 0; ct < 4; ct++) {
            const size_t wo = (((size_t)kb * 8 + (wv * 4 + ct)) * 64 + lane) * 8;
            bh[ct] = *(const bf16x8*)(W1hi + wo);
            bl[ct] = *(const bf16x8*)(W1lo + wo);
        }
        if (kb < 3) {
            const size_t o = (size_t)(kb + 1) * 32;
            ph0 = *(const uint4*)(Ah + ga0 + o);
            ph1 = *(const uint4*)(Ah + ga1 + o);
        }
        bf16x8 ah[4];
#pragma unroll
        for (int rt = 0; rt < 4; rt++) {
            int off = cur * 4096 + (rt * 16 + c) * 32 + g * 8;
            ah[rt] = *(bf16x8*)&smem[off];
        }
#pragma unroll
        for (int rt = 0; rt < 4; rt++)
#pragma unroll
            for (int ct = 0; ct < 4; ct++) {
                acc[rt][ct] = __builtin_amdgcn_mfma_f32_16x16x32_bf16(ah[rt], bh[ct], acc[rt][ct], 0, 0, 0);
                acc[rt][ct] = __builtin_amdgcn_mfma_f32_16x16x32_bf16(ah[rt], bl[ct], acc[rt][ct], 0, 0, 0);
            }
        if (kb < 3) {
            *(uint4*)&smem[(cur ^ 1) * 4096 + la0] = ph0;
            *(uint4*)&smem[(cur ^ 1) * 4096 + la1] = ph1;
        }
        __syncthreads();   // final iter: all A reads done -> H may overwrite
        cur ^= 1;
    }

    // ---------------- BN + ReLU -> H (bf16)
    {
        float cs[4], ca[4];
#pragma unroll
        for (int ct = 0; ct < 4; ct++) {
            int n = wv * 64 + ct * 16 + c;
            float s = gm[n] * rsqrtf(rv[n] + BN_EPS);
            cs[ct] = s;
            ca[ct] = (b1[n] - rm[n]) * s + bt[n];
        }
#pragma unroll
        for (int rt = 0; rt < 4; rt++)
#pragma unroll
            for (int r = 0; r < 4; r++) {
                int row = rt * 16 + g * 4 + r;
#pragma unroll
                for (int ct = 0; ct < 4; ct++) {
                    int col = wv * 64 + ct * 16 + c;
                    float v = fmaxf(acc[rt][ct][r] * cs[ct] + ca[ct], 0.f);
                    smem[row * 136 + col] = f2b(v);
                }
            }
    }
    __syncthreads();

    // ---------------- phase 2: H @ W2 (2 terms)
#pragma unroll
    for (int i = 0; i < 4; i++)
#pragma unroll
        for (int j = 0; j < 4; j++) acc[i][j] = (f32x4){0.f, 0.f, 0.f, 0.f};

    for (int kb = 0; kb < 4; kb++) {
        bf16x8 bh[4], bl[4];
#pragma unroll
        for (int ct = 0; ct < 4; ct++) {
            const size_t wo = (((size_t)kb * 8 + (wv * 4 + ct)) * 64 + lane) * 8;
            bh[ct] = *(const bf16x8*)(W2hi + wo);
            bl[ct] = *(const bf16x8*)(W2lo + wo);
        }
        bf16x8 ah[4];
#pragma unroll
        for (int rt = 0; rt < 4; rt++) {
            int off = (rt * 16 + c) * 136 + kb * 32 + g * 8;
            ah[rt] = *(bf16x8*)&smem[off];
        }
#pragma unroll
        for (int rt = 0; rt < 4; rt++)
#pragma unroll
            for (int ct = 0; ct < 4; ct++) {
                acc[rt][ct] = __builtin_amdgcn_mfma_f32_16x16x32_bf16(ah[rt], bh[ct], acc[rt][ct], 0, 0, 0);
                acc[rt][ct] = __builtin_amdgcn_mfma_f32_16x16x32_bf16(ah[rt], bl[ct], acc[rt][ct], 0, 0, 0);
            }
    }
    __syncthreads();   // all H reads done -> P may overwrite smem

    // ---------------- epilogue: +b2 (,ReLU) -> bf16 plane + LDS P (bf16)
    {
        float ca2[4];
#pragma unroll
        for (int ct = 0; ct < 4; ct++) ca2[ct] = b2[wv * 64 + ct * 16 + c];
#pragma unroll
        for (int rt = 0; rt < 4; rt++)
#pragma unroll
            for (int r = 0; r < 4; r++) {
                int rl = rt * 16 + g * 4 + r;
                int row = row0 + rl;
                bool valid = row < M;
#pragma unroll
                for (int ct = 0; ct < 4; ct++) {
                    int col = wv * 64 + ct * 16 + c;
                    float v = acc[rt][ct][r] + ca2[ct];
                    if (RELU_OUT) v = fmaxf(v, 0.f);
                    ushort hh = f2b(valid ? v : 0.f);
                    smem[rl * 136 + col] = hh;
                    if (WRITE_PLANES && valid) Ch[(size_t)row * 128 + col] = hh;
                }
            }
    }
    __syncthreads();

    // ---------------- fused mean-pool contribution (batch is sorted)
    {
        int col = t;              // 0..127
        int gcur = bsm[0];
        float accp = 0.f;
#pragma unroll 8
        for (int r = 0; r < 64; r++) {
            int gg = bsm[r];
            if (gg != gcur) {     // block-uniform branch (sorted batch)
                if (gcur >= 0) atomicAdd(&pooled[gcur * 384 + poff + col], accp);
                accp = 0.f;
                gcur = gg;
            }
            accp += b2f(smem[r * 136 + col]);
        }
        if (gcur >= 0) atomicAdd(&pooled[gcur * 384 + poff + col], accp);
    }
}

// ------------------------------------------------------------------- final
__global__ __launch_bounds__(128) void final_kernel(const float* __restrict__ pooled,
                                                    const int* __restrict__ batch,
                                                    const float* __restrict__ W,
                                                    const float* __restrict__ b,
                                                    float* __restrict__ out, int n) {
    __shared__ float ps[384];
    int gph = blockIdx.x, t = threadIdx.x;
    int lo1 = 0, hi1 = n;
    while (lo1 < hi1) { int mid = (lo1 + hi1) >> 1; if (batch[mid] < gph) lo1 = mid + 1; else hi1 = mid; }
    int start = lo1;
    int lo2 = start, hi2 = n;
    while (lo2 < hi2) { int mid = (lo2 + hi2) >> 1; if (batch[mid] < gph + 1) lo2 = mid + 1; else hi2 = mid; }
    int cnt = lo2 - start;
    float inv = 1.f / (float)(cnt > 0 ? cnt : 1);
    for (int i = t; i < 384; i += 128) ps[i] = pooled[gph * 384 + i] * inv;
    __syncthreads();
    float acc = b[t];
#pragma unroll 8
    for (int k = 0; k < 384; k++) acc += ps[k] * W[k * 128 + t];
    out[gph * 128 + t] = acc;
}

// ------------------------------------------------------------------ launch
extern "C" void kernel_launch(void* const* d_in, const int* in_sizes, int n_in,
                              void* d_out, int out_size, void* d_ws, size_t ws_size,
                              hipStream_t stream) {
    const float* x     = (const float*)d_in[0];
    const int*   edge  = (const int*)d_in[1];
    const int*   batch = (const int*)d_in[2];
    const float* p[32];
    for (int i = 0; i < n_in && i < 32; i++) p[i] = (const float*)d_in[i];
    const float* lin_W = p[27];
    const float* lin_b = p[28];

    char* w = (char*)d_ws;
    auto alloc = [&](size_t bytes) { void* r = (void*)w; w += (bytes + 255) & ~(size_t)255; return r; };
    const size_t PL = (size_t)NNODES * 128;
    ushort* thi   = (ushort*)alloc(PL * 2);   // agg out plane
    ushort* xh0   = (ushort*)alloc(PL * 2);   // bf16(x); dead after agg L1
    ushort* p1h   = (ushort*)alloc(PL * 2);
    ushort* p2h   = xh0;                      // alias: xh0 dead before mlp L2 writes
    float* pooled = (float*)alloc((size_t)NGRAPHS * 384 * 4);
    int* counts   = (int*)alloc((size_t)NNODES * 4);
    int* cursor   = (int*)alloc((size_t)NNODES * 4);
    int* row_ptr  = (int*)alloc((size_t)(NNODES + 1) * 4);
    int* esrc     = (int*)alloc((size_t)NEDGES * 4);
    int* partials = (int*)alloc(256 * 4);
    ushort* wt_hi = (ushort*)alloc((size_t)6 * 16384 * 2);
    ushort* wt_lo = (ushort*)alloc((size_t)6 * 16384 * 2);

    const int* src = edge;
    const int* dst = edge + NEDGES;

    // --- setup: ONE cooperative dispatch (zero+convert+wsplit+hist+scan+scatter)
    {
        const float* W0 = p[3], *W1 = p[9], *W2 = p[11], *W3 = p[17], *W4 = p[19], *W5 = p[25];
        void* args[] = {(void*)&x, (void*)&xh0, (void*)&pooled,
                        (void*)&src, (void*)&dst,
                        (void*)&counts, (void*)&cursor, (void*)&row_ptr,
                        (void*)&esrc, (void*)&partials,
                        (void*)&W0, (void*)&W1, (void*)&W2,
                        (void*)&W3, (void*)&W4, (void*)&W5,
                        (void*)&wt_hi, (void*)&wt_lo};
        hipLaunchCooperativeKernel((void*)setup_kernel, dim3(1024), dim3(256),
                                   args, 0, stream);
    }

    // --- 3 GIN layers (mlp fuses the mean-pool contribution)
    int mlp_grid = (NNODES + 63) / 64;              // 782
    int agg_grid = (NNODES / 4 * 64 + 255) / 256;   // 3125

    // layer 1 (self from bf16 plane — same rounding class as neighbors)
    agg_kernel<<<agg_grid, 256, 0, stream>>>(xh0, row_ptr, esrc, thi, NNODES);
    mlp_kernel<true, true><<<mlp_grid, 128, 0, stream>>>(thi,
        wt_hi + 0 * 16384, wt_lo + 0 * 16384, wt_hi + 1 * 16384, wt_lo + 1 * 16384,
        p[4], p[5], p[6], p[7], p[8], p[10], p1h, batch, pooled, 0, NNODES);
    // layer 2
    agg_kernel<<<agg_grid, 256, 0, stream>>>(p1h, row_ptr, esrc, thi, NNODES);
    mlp_kernel<true, true><<<mlp_grid, 128, 0, stream>>>(thi,
        wt_hi + 2 * 16384, wt_lo + 2 * 16384, wt_hi + 3 * 16384, wt_lo + 3 * 16384,
        p[12], p[13], p[14], p[15], p[16], p[18], p2h, batch, pooled, 128, NNODES);
    // layer 3 (no relu, no plane writes — pool-only output)
    agg_kernel<<<agg_grid, 256, 0, stream>>>(p2h, row_ptr, esrc, thi, NNODES);
    mlp_kernel<false, false><<<mlp_grid, 128, 0, stream>>>(thi,
        wt_hi + 4 * 16384, wt_lo + 4 * 16384, wt_hi + 5 * 16384, wt_lo + 5 * 16384,
        p[20], p[21], p[22], p[23], p[24], p[26], nullptr, batch, pooled, 256, NNODES);

    // --- final linear on mean-pooled JK-concat
    final_kernel<<<NGRAPHS, 128, 0, stream>>>(pooled, batch, lin_W, lin_b,
                                              (float*)d_out, NNODES);
}

// Round 9
// 405.369 us; speedup vs baseline: 1.9328x; 1.9328x over previous
//
#include <hip/hip_runtime.h>
#include <hip/hip_bf16.h>

#define NNODES 50000
#define NEDGES 600000
#define NGRAPHS 512
#define BN_EPS 1e-5f

typedef short bf16x8 __attribute__((ext_vector_type(8)));
typedef float f32x4 __attribute__((ext_vector_type(4)));

// split fp32 -> hi/lo bf16 (RNE); hi+lo carries ~16 mantissa bits (weights only)
__device__ __forceinline__ void bf_split(float x, ushort& h, ushort& l) {
    __hip_bfloat16 bh = __float2bfloat16(x);
    float r = x - __bfloat162float(bh);
    __hip_bfloat16 bl = __float2bfloat16(r);
    h = __builtin_bit_cast(ushort, bh);
    l = __builtin_bit_cast(ushort, bl);
}
__device__ __forceinline__ ushort f2b(float x) {
    return __builtin_bit_cast(ushort, __float2bfloat16(x));
}
__device__ __forceinline__ float b2f(ushort u) {
    union { uint i; float f; } c; c.i = ((uint)u) << 16; return c.f;
}
// bf16 pair unpack from a packed uint: lo = shift, hi = mask (1 VALU each)
__device__ __forceinline__ float blo(uint u) {
    union { uint i; float f; } c; c.i = u << 16; return c.f;
}
__device__ __forceinline__ float bhi(uint u) {
    union { uint i; float f; } c; c.i = u & 0xffff0000u; return c.f;
}

// exact 8-term pairwise tree per packed channel (R4-proven order)
#define TREE8(A, v0, v1, v2, v3, v4, v5, v6, v7)                               \
    A[0] += ((blo(v0.x) + blo(v1.x)) + (blo(v2.x) + blo(v3.x))) +              \
            ((blo(v4.x) + blo(v5.x)) + (blo(v6.x) + blo(v7.x)));               \
    A[1] += ((bhi(v0.x) + bhi(v1.x)) + (bhi(v2.x) + bhi(v3.x))) +              \
            ((bhi(v4.x) + bhi(v5.x)) + (bhi(v6.x) + bhi(v7.x)));               \
    A[2] += ((blo(v0.y) + blo(v1.y)) + (blo(v2.y) + blo(v3.y))) +              \
            ((blo(v4.y) + blo(v5.y)) + (blo(v6.y) + blo(v7.y)));               \
    A[3] += ((bhi(v0.y) + bhi(v1.y)) + (bhi(v2.y) + bhi(v3.y))) +              \
            ((bhi(v4.y) + bhi(v5.y)) + (bhi(v6.y) + bhi(v7.y)));               \
    A[4] += ((blo(v0.z) + blo(v1.z)) + (blo(v2.z) + blo(v3.z))) +              \
            ((blo(v4.z) + blo(v5.z)) + (blo(v6.z) + blo(v7.z)));               \
    A[5] += ((bhi(v0.z) + bhi(v1.z)) + (bhi(v2.z) + bhi(v3.z))) +              \
            ((bhi(v4.z) + bhi(v5.z)) + (bhi(v6.z) + bhi(v7.z)));               \
    A[6] += ((blo(v0.w) + blo(v1.w)) + (blo(v2.w) + blo(v3.w))) +              \
            ((blo(v4.w) + blo(v5.w)) + (blo(v6.w) + blo(v7.w)));               \
    A[7] += ((bhi(v0.w) + bhi(v1.w)) + (bhi(v2.w) + bhi(v3.w))) +              \
            ((bhi(v4.w) + bhi(v5.w)) + (bhi(v6.w) + bhi(v7.w)));

// load-8 + tree (tail helper)
#define GB8U(A, E)                                                             \
    {                                                                          \
        int i0 = esrc[E],     i1 = esrc[E + 1], i2 = esrc[E + 2], i3 = esrc[E + 3]; \
        int i4 = esrc[E + 4], i5 = esrc[E + 5], i6 = esrc[E + 6], i7 = esrc[E + 7]; \
        uint4 v0 = xv[(size_t)i0 * 16 + q];                                    \
        uint4 v1 = xv[(size_t)i1 * 16 + q];                                    \
        uint4 v2 = xv[(size_t)i2 * 16 + q];                                    \
        uint4 v3 = xv[(size_t)i3 * 16 + q];                                    \
        uint4 v4 = xv[(size_t)i4 * 16 + q];                                    \
        uint4 v5 = xv[(size_t)i5 * 16 + q];                                    \
        uint4 v6 = xv[(size_t)i6 * 16 + q];                                    \
        uint4 v7 = xv[(size_t)i7 * 16 + q];                                    \
        TREE8(A, v0, v1, v2, v3, v4, v5, v6, v7)                               \
    }

// 2-edge and 1-edge tails
#define GB2U(A, E)                                                             \
    {                                                                          \
        int i0 = esrc[E], i1 = esrc[E + 1];                                    \
        uint4 v0 = xv[(size_t)i0 * 16 + q];                                    \
        uint4 v1 = xv[(size_t)i1 * 16 + q];                                    \
        A[0] += blo(v0.x) + blo(v1.x); A[1] += bhi(v0.x) + bhi(v1.x);          \
        A[2] += blo(v0.y) + blo(v1.y); A[3] += bhi(v0.y) + bhi(v1.y);          \
        A[4] += blo(v0.z) + blo(v1.z); A[5] += bhi(v0.z) + bhi(v1.z);          \
        A[6] += blo(v0.w) + blo(v1.w); A[7] += bhi(v0.w) + bhi(v1.w);          \
    }
#define GB1U(A, E)                                                             \
    {                                                                          \
        uint4 v = xv[(size_t)esrc[E] * 16 + q];                                \
        A[0] += blo(v.x); A[1] += bhi(v.x);                                    \
        A[2] += blo(v.y); A[3] += bhi(v.y);                                    \
        A[4] += blo(v.z); A[5] += bhi(v.z);                                    \
        A[6] += blo(v.w); A[7] += bhi(v.w);                                    \
    }

// ------------------------------------------------------------------- prep
// One dispatch: x->bf16 (blocks 0..3124), zero pooled (3125..3316), hist
// over edges (3317..5660; counts pre-zeroed via hipMemsetAsync), wsplit 6
// matrices in MFMA-FRAGMENT ORDER (5661..5756), row_ptr[N] init.
__global__ __launch_bounds__(256) void prep_kernel(
    const float* __restrict__ x, ushort* __restrict__ xh,
    float* __restrict__ pooled, const int* __restrict__ dst,
    int* __restrict__ counts, int* __restrict__ row_ptr,
    const float* W0, const float* W1, const float* W2, const float* W3,
    const float* W4, const float* W5, ushort* __restrict__ hi, ushort* __restrict__ lo) {
    int b = blockIdx.x, t = threadIdx.x;
    if (b < 3125) {                                 // x: 6.4M floats -> bf16
        int f4 = b * 512 + t * 2;
        float4 a0 = ((const float4*)x)[f4];
        float4 a1 = ((const float4*)x)[f4 + 1];
        ushort4 u0 = {f2b(a0.x), f2b(a0.y), f2b(a0.z), f2b(a0.w)};
        ushort4 u1 = {f2b(a1.x), f2b(a1.y), f2b(a1.z), f2b(a1.w)};
        int e0 = f4 * 4;
        *(ushort4*)(xh + e0) = u0;
        *(ushort4*)(xh + e0 + 4) = u1;
        if (b == 0 && t == 0) row_ptr[NNODES] = NEDGES;
    } else if (b < 3317) {                          // pooled: 512*384 floats
        ((float4*)pooled)[(b - 3125) * 256 + t] = make_float4(0.f, 0.f, 0.f, 0.f);
    } else if (b < 5661) {                          // hist: 600000 edges
        int i = (b - 3317) * 256 + t;
        if (i < NEDGES) atomicAdd(&counts[dst[i]], 1);
    } else {                                        // wsplit: 96 blocks
        int wb = b - 5661;
        const float* Ws[6] = {W0, W1, W2, W3, W4, W5};
        const float* W = Ws[wb >> 4];
        ushort* h = hi + (size_t)(wb >> 4) * 16384;
        ushort* l = lo + (size_t)(wb >> 4) * 16384;
        int chunk = wb & 15;
#pragma unroll
        for (int i = 0; i < 4; i++) {
            int idx = chunk * 1024 + i * 256 + t;   // 0..16383 frag-order slot
            int j    = idx & 7;
            int lane = (idx >> 3) & 63;
            int nt   = (idx >> 9) & 7;
            int kb   = (idx >> 12) & 3;
            int k = kb * 32 + ((lane >> 4) << 3) + j;
            int n = nt * 16 + (lane & 15);
            ushort hh, ll;
            bf_split(W[k * 128 + n], hh, ll);
            h[idx] = hh;
            l[idx] = ll;
        }
    }
}

// ------------------------------------------------- fused scan (scan1+scan3)
// Block b: base = sum(counts[0..b*256)) via thread-parallel re-reduction
// (identical integer value to the partials route), then the exact scan3
// intra-chunk exclusive scan. One dispatch instead of two.
__global__ __launch_bounds__(256) void scan_kernel(const int* __restrict__ counts,
                                                   int* __restrict__ row_ptr,
                                                   int* __restrict__ cursor, int n) {
    __shared__ int s[256];
    __shared__ int base_sh;
    int t = threadIdx.x;
    int start = blockIdx.x * 256;
    int partial = 0;
    for (int i = t; i < start; i += 256) partial += counts[i];
    s[t] = partial;
    __syncthreads();
    for (int off = 128; off > 0; off >>= 1) {
        if (t < off) s[t] += s[t + off];
        __syncthreads();
    }
    if (t == 0) base_sh = s[0];
    __syncthreads();
    int base = base_sh;
    int i = start + t;
    int v = (i < n) ? counts[i] : 0;
    __syncthreads();
    s[t] = v;
    __syncthreads();
    for (int off = 1; off < 256; off <<= 1) {
        int nv = (t >= off) ? s[t - off] : 0;
        __syncthreads();
        s[t] += nv;
        __syncthreads();
    }
    if (i < n) {
        int ex = base + s[t] - v;   // exclusive
        row_ptr[i] = ex;
        cursor[i] = ex;
    }
}

__global__ __launch_bounds__(256) void scatter_kernel(const int* __restrict__ src,
                                                      const int* __restrict__ dst,
                                                      int* __restrict__ cursor,
                                                      int* __restrict__ esrc, int E) {
    int i = blockIdx.x * 256 + threadIdx.x;
    if (i < E) {
        int p = atomicAdd(&cursor[dst[i]], 1);
        esrc[p] = src[i];
    }
}

// --------------------------------------------------- fused layer (agg + MLP)
// R7: 256-thread (4-wave) blocks fix R3's occupancy failure. Gather: R4's
// exact per-node geometry (16 lanes x 8ch uint4, 8/2/1 pairwise trees),
// dual-node interleave (16 outstanding loads/lane), 2 iterations x 8 nodes
// per wave -> 64 rows/block straight into LDS A[kb][m][32]. 782 blocks x
// ~4/CU -> whole grid resident (3128 gather waves vs R3's 1564 at 13.8%
// occupancy). MLP: 4-way column split (acc[4][2]); same total MFMA count,
// same per-output accumulation order -> bitwise identical. Kills the thi
// plane round-trip and one dispatch boundary per layer.
template <bool RELU_OUT, bool WRITE_PLANES>
__global__ __launch_bounds__(256) void layer_kernel(
    const ushort* __restrict__ Pin,
    const int* __restrict__ rp, const int* __restrict__ esrc,
    const ushort* __restrict__ W1hi, const ushort* __restrict__ W1lo,
    const ushort* __restrict__ W2hi, const ushort* __restrict__ W2lo,
    const float* __restrict__ b1, const float* __restrict__ gm,
    const float* __restrict__ bt, const float* __restrict__ rm,
    const float* __restrict__ rv, const float* __restrict__ b2,
    ushort* __restrict__ Ch,
    const int* __restrict__ batch, float* __restrict__ pooled, int poff, int M) {
    __shared__ __align__(16) ushort smem[64 * 136];   // 17408 B (A-chunks, then H/P)
    __shared__ int bsm[64];
    const int t = threadIdx.x;            // 0..255
    const int lane = t & 63;
    const int wv = t >> 6;                // wave 0..3 (col quarter in MLP)
    const int row0 = blockIdx.x * 64;
    const int g = lane >> 4, c = lane & 15;

    if (t < 64) bsm[t] = (row0 + t < M) ? batch[row0 + t] : -1;

    // ---------------- gather: 16 rows/wave -> LDS A[kb][m][32] (bf16)
    {
        const int grp = lane >> 4;        // 16-lane group 0..3
        const int q   = lane & 15;        // 16B granule: channels q*8..q*8+7
        const uint4* xv = (const uint4*)Pin;
        for (int it = 0; it < 2; it++) {
            const int mA = wv * 16 + it * 8 + grp * 2, mB = mA + 1;
            const int nA = row0 + mA, nB = row0 + mB;
            float aA[8] = {0.f, 0.f, 0.f, 0.f, 0.f, 0.f, 0.f, 0.f};
            float aB[8] = {0.f, 0.f, 0.f, 0.f, 0.f, 0.f, 0.f, 0.f};
            int eA = 0, endA = 0, eB = 0, endB = 0;
            if (nA < M) {
                uint4 s0 = xv[(size_t)nA * 16 + q];
                aA[0] = blo(s0.x); aA[1] = bhi(s0.x);
                aA[2] = blo(s0.y); aA[3] = bhi(s0.y);
                aA[4] = blo(s0.z); aA[5] = bhi(s0.z);
                aA[6] = blo(s0.w); aA[7] = bhi(s0.w);
                eA = rp[nA]; endA = rp[nA + 1];
            }
            if (nB < M) {
                uint4 s0 = xv[(size_t)nB * 16 + q];
                aB[0] = blo(s0.x); aB[1] = bhi(s0.x);
                aB[2] = blo(s0.y); aB[3] = bhi(s0.y);
                aB[4] = blo(s0.z); aB[5] = bhi(s0.z);
                aB[6] = blo(s0.w); aB[7] = bhi(s0.w);
                eB = rp[nB]; endB = rp[nB + 1];
            }
            // interleaved main: 16 outstanding gathers (8 per node)
            while (eA + 8 <= endA && eB + 8 <= endB) {
                int a0 = esrc[eA],     a1 = esrc[eA + 1], a2 = esrc[eA + 2], a3 = esrc[eA + 3];
                int a4 = esrc[eA + 4], a5 = esrc[eA + 5], a6 = esrc[eA + 6], a7 = esrc[eA + 7];
                int b0 = esrc[eB],     b1_ = esrc[eB + 1], b2_ = esrc[eB + 2], b3 = esrc[eB + 3];
                int b4 = esrc[eB + 4], b5 = esrc[eB + 5], b6 = esrc[eB + 6], b7 = esrc[eB + 7];
                uint4 vA0 = xv[(size_t)a0 * 16 + q], vA1 = xv[(size_t)a1 * 16 + q];
                uint4 vA2 = xv[(size_t)a2 * 16 + q], vA3 = xv[(size_t)a3 * 16 + q];
                uint4 vA4 = xv[(size_t)a4 * 16 + q], vA5 = xv[(size_t)a5 * 16 + q];
                uint4 vA6 = xv[(size_t)a6 * 16 + q], vA7 = xv[(size_t)a7 * 16 + q];
                uint4 vB0 = xv[(size_t)b0 * 16 + q], vB1 = xv[(size_t)b1_ * 16 + q];
                uint4 vB2 = xv[(size_t)b2_ * 16 + q], vB3 = xv[(size_t)b3 * 16 + q];
                uint4 vB4 = xv[(size_t)b4 * 16 + q], vB5 = xv[(size_t)b5 * 16 + q];
                uint4 vB6 = xv[(size_t)b6 * 16 + q], vB7 = xv[(size_t)b7 * 16 + q];
                TREE8(aA, vA0, vA1, vA2, vA3, vA4, vA5, vA6, vA7)
                TREE8(aB, vB0, vB1, vB2, vB3, vB4, vB5, vB6, vB7)
                eA += 8; eB += 8;
            }
            for (; eA + 8 <= endA; eA += 8) GB8U(aA, eA);
            for (; eB + 8 <= endB; eB += 8) GB8U(aB, eB);
            for (; eA + 2 <= endA; eA += 2) GB2U(aA, eA);
            for (; eA < endA; eA++) GB1U(aA, eA);
            for (; eB + 2 <= endB; eB += 2) GB2U(aB, eB);
            for (; eB < endB; eB++) GB1U(aB, eB);
            // pack bf16 -> LDS A-chunk: ushort idx (q>>2)*2048 + m*32 + (q&3)*8
            uint4 oA, oB;
            oA.x = (uint)f2b(aA[0]) | ((uint)f2b(aA[1]) << 16);
            oA.y = (uint)f2b(aA[2]) | ((uint)f2b(aA[3]) << 16);
            oA.z = (uint)f2b(aA[4]) | ((uint)f2b(aA[5]) << 16);
            oA.w = (uint)f2b(aA[6]) | ((uint)f2b(aA[7]) << 16);
            oB.x = (uint)f2b(aB[0]) | ((uint)f2b(aB[1]) << 16);
            oB.y = (uint)f2b(aB[2]) | ((uint)f2b(aB[3]) << 16);
            oB.z = (uint)f2b(aB[4]) | ((uint)f2b(aB[5]) << 16);
            oB.w = (uint)f2b(aB[6]) | ((uint)f2b(aB[7]) << 16);
            *(uint4*)&smem[(q >> 2) * 2048 + mA * 32 + (q & 3) * 8] = oA;
            *(uint4*)&smem[(q >> 2) * 2048 + mB * 32 + (q & 3) * 8] = oB;
        }
    }
    __syncthreads();

    f32x4 acc[4][2];
#pragma unroll
    for (int i = 0; i < 4; i++)
#pragma unroll
        for (int j = 0; j < 2; j++) acc[i][j] = (f32x4){0.f, 0.f, 0.f, 0.f};

    // ---------------- phase 1: A @ W1 (2 terms); A read-only, no barriers
    for (int kb = 0; kb < 4; kb++) {
        bf16x8 bh[2], bl[2];
#pragma unroll
        for (int ct = 0; ct < 2; ct++) {
            const size_t wo = (((size_t)kb * 8 + (wv * 2 + ct)) * 64 + lane) * 8;
            bh[ct] = *(const bf16x8*)(W1hi + wo);
            bl[ct] = *(const bf16x8*)(W1lo + wo);
        }
        bf16x8 ah[4];
#pragma unroll
        for (int rt = 0; rt < 4; rt++) {
            int off = kb * 2048 + (rt * 16 + c) * 32 + g * 8;
            ah[rt] = *(bf16x8*)&smem[off];
        }
#pragma unroll
        for (int rt = 0; rt < 4; rt++)
#pragma unroll
            for (int ct = 0; ct < 2; ct++) {
                acc[rt][ct] = __builtin_amdgcn_mfma_f32_16x16x32_bf16(ah[rt], bh[ct], acc[rt][ct], 0, 0, 0);
                acc[rt][ct] = __builtin_amdgcn_mfma_f32_16x16x32_bf16(ah[rt], bl[ct], acc[rt][ct], 0, 0, 0);
            }
    }
    __syncthreads();   // all A reads done -> H may overwrite smem

    // ---------------- BN + ReLU -> H (bf16)
    {
        float cs[2], ca[2];
#pragma unroll
        for (int ct = 0; ct < 2; ct++) {
            int n = wv * 32 + ct * 16 + c;
            float s = gm[n] * rsqrtf(rv[n] + BN_EPS);
            cs[ct] = s;
            ca[ct] = (b1[n] - rm[n]) * s + bt[n];
        }
#pragma unroll
        for (int rt = 0; rt < 4; rt++)
#pragma unroll
            for (int r = 0; r < 4; r++) {
                int row = rt * 16 + g * 4 + r;
#pragma unroll
                for (int ct = 0; ct < 2; ct++) {
                    int col = wv * 32 + ct * 16 + c;
                    float v = fmaxf(acc[rt][ct][r] * cs[ct] + ca[ct], 0.f);
                    smem[row * 136 + col] = f2b(v);
                }
            }
    }
    __syncthreads();

    // ---------------- phase 2: H @ W2 (2 terms)
#pragma unroll
    for (int i = 0; i < 4; i++)
#pragma unroll
        for (int j = 0; j < 2; j++) acc[i][j] = (f32x4){0.f, 0.f, 0.f, 0.f};

    for (int kb = 0; kb < 4; kb++) {
        bf16x8 bh[2], bl[2];
#pragma unroll
        for (int ct = 0; ct < 2; ct++) {
            const size_t wo = (((size_t)kb * 8 + (wv * 2 + ct)) * 64 + lane) * 8;
            bh[ct] = *(const bf16x8*)(W2hi + wo);
            bl[ct] = *(const bf16x8*)(W2lo + wo);
        }
        bf16x8 ah[4];
#pragma unroll
        for (int rt = 0; rt < 4; rt++) {
            int off = (rt * 16 + c) * 136 + kb * 32 + g * 8;
            ah[rt] = *(bf16x8*)&smem[off];
        }
#pragma unroll
        for (int rt = 0; rt < 4; rt++)
#pragma unroll
            for (int ct = 0; ct < 2; ct++) {
                acc[rt][ct] = __builtin_amdgcn_mfma_f32_16x16x32_bf16(ah[rt], bh[ct], acc[rt][ct], 0, 0, 0);
                acc[rt][ct] = __builtin_amdgcn_mfma_f32_16x16x32_bf16(ah[rt], bl[ct], acc[rt][ct], 0, 0, 0);
            }
    }
    __syncthreads();   // all H reads done -> P may overwrite smem

    // ---------------- epilogue: +b2 (,ReLU) -> bf16 plane + LDS P (bf16)
    {
        float ca2[2];
#pragma unroll
        for (int ct = 0; ct < 2; ct++) ca2[ct] = b2[wv * 32 + ct * 16 + c];
#pragma unroll
        for (int rt = 0; rt < 4; rt++)
#pragma unroll
            for (int r = 0; r < 4; r++) {
                int rl = rt * 16 + g * 4 + r;
                int row = row0 + rl;
                bool valid = row < M;
#pragma unroll
                for (int ct = 0; ct < 2; ct++) {
                    int col = wv * 32 + ct * 16 + c;
                    float v = acc[rt][ct][r] + ca2[ct];
                    if (RELU_OUT) v = fmaxf(v, 0.f);
                    ushort hh = f2b(valid ? v : 0.f);
                    smem[rl * 136 + col] = hh;
                    if (WRITE_PLANES && valid) Ch[(size_t)row * 128 + col] = hh;
                }
            }
    }
    __syncthreads();

    // ---------------- fused mean-pool contribution (batch is sorted)
    if (t < 128) {
        int col = t;              // 0..127
        int gcur = bsm[0];
        float accp = 0.f;
#pragma unroll 8
        for (int r = 0; r < 64; r++) {
            int gg = bsm[r];
            if (gg != gcur) {     // block-uniform branch (sorted batch)
                if (gcur >= 0) atomicAdd(&pooled[gcur * 384 + poff + col], accp);
                accp = 0.f;
                gcur = gg;
            }
            accp += b2f(smem[r * 136 + col]);
        }
        if (gcur >= 0) atomicAdd(&pooled[gcur * 384 + poff + col], accp);
    }
}

// ------------------------------------------------------------------- final
__global__ __launch_bounds__(128) void final_kernel(const float* __restrict__ pooled,
                                                    const int* __restrict__ batch,
                                                    const float* __restrict__ W,
                                                    const float* __restrict__ b,
                                                    float* __restrict__ out, int n) {
    __shared__ float ps[384];
    int gph = blockIdx.x, t = threadIdx.x;
    int lo1 = 0, hi1 = n;
    while (lo1 < hi1) { int mid = (lo1 + hi1) >> 1; if (batch[mid] < gph) lo1 = mid + 1; else hi1 = mid; }
    int start = lo1;
    int lo2 = start, hi2 = n;
    while (lo2 < hi2) { int mid = (lo2 + hi2) >> 1; if (batch[mid] < gph + 1) lo2 = mid + 1; else hi2 = mid; }
    int cnt = lo2 - start;
    float inv = 1.f / (float)(cnt > 0 ? cnt : 1);
    for (int i = t; i < 384; i += 128) ps[i] = pooled[gph * 384 + i] * inv;
    __syncthreads();
    float acc = b[t];
#pragma unroll 8
    for (int k = 0; k < 384; k++) acc += ps[k] * W[k * 128 + t];
    out[gph * 128 + t] = acc;
}

// ------------------------------------------------------------------ launch
extern "C" void kernel_launch(void* const* d_in, const int* in_sizes, int n_in,
                              void* d_out, int out_size, void* d_ws, size_t ws_size,
                              hipStream_t stream) {
    const float* x     = (const float*)d_in[0];
    const int*   edge  = (const int*)d_in[1];
    const int*   batch = (const int*)d_in[2];
    const float* p[32];
    for (int i = 0; i < n_in && i < 32; i++) p[i] = (const float*)d_in[i];
    const float* lin_W = p[27];
    const float* lin_b = p[28];

    char* w = (char*)d_ws;
    auto alloc = [&](size_t bytes) { void* r = (void*)w; w += (bytes + 255) & ~(size_t)255; return r; };
    const size_t PL = (size_t)NNODES * 128;
    ushort* xh0   = (ushort*)alloc(PL * 2);   // bf16(x); dead after layer-1 gather
    ushort* p1h   = (ushort*)alloc(PL * 2);
    ushort* p2h   = xh0;                      // alias: xh0 dead before layer-2 writes
    float* pooled = (float*)alloc((size_t)NGRAPHS * 384 * 4);
    int* counts   = (int*)alloc((size_t)NNODES * 4);
    int* cursor   = (int*)alloc((size_t)NNODES * 4);
    int* row_ptr  = (int*)alloc((size_t)(NNODES + 1) * 4);
    int* esrc     = (int*)alloc((size_t)NEDGES * 4);
    ushort* wt_hi = (ushort*)alloc((size_t)6 * 16384 * 2);
    ushort* wt_lo = (ushort*)alloc((size_t)6 * 16384 * 2);

    const int* src = edge;
    const int* dst = edge + NEDGES;

    // --- zero counts (stream-ordered), then prep incl. hist + frag wsplit
    hipMemsetAsync(counts, 0, (size_t)NNODES * 4, stream);
    prep_kernel<<<5757, 256, 0, stream>>>(x, xh0, pooled, dst, counts, row_ptr,
                                          p[3], p[9], p[11], p[17], p[19], p[25],
                                          wt_hi, wt_lo);

    // --- CSR build: 2 dispatches (fused scan, then scatter)
    int nb = (NNODES + 255) / 256;  // 196
    scan_kernel<<<nb, 256, 0, stream>>>(counts, row_ptr, cursor, NNODES);
    scatter_kernel<<<(NEDGES + 255) / 256, 256, 0, stream>>>(src, dst, cursor, esrc, NEDGES);

    // --- 3 fused GIN layers (gather + MLP + mean-pool contribution)
    int grid = (NNODES + 63) / 64;              // 782
    layer_kernel<true, true><<<grid, 256, 0, stream>>>(xh0, row_ptr, esrc,
        wt_hi + 0 * 16384, wt_lo + 0 * 16384, wt_hi + 1 * 16384, wt_lo + 1 * 16384,
        p[4], p[5], p[6], p[7], p[8], p[10], p1h, batch, pooled, 0, NNODES);
    layer_kernel<true, true><<<grid, 256, 0, stream>>>(p1h, row_ptr, esrc,
        wt_hi + 2 * 16384, wt_lo + 2 * 16384, wt_hi + 3 * 16384, wt_lo + 3 * 16384,
        p[12], p[13], p[14], p[15], p[16], p[18], p2h, batch, pooled, 128, NNODES);
    layer_kernel<false, false><<<grid, 256, 0, stream>>>(p2h, row_ptr, esrc,
        wt_hi + 4 * 16384, wt_lo + 4 * 16384, wt_hi + 5 * 16384, wt_lo + 5 * 16384,
        p[20], p[21], p[22], p[23], p[24], p[26], nullptr, batch, pooled, 256, NNODES);

    // --- final linear on mean-pooled JK-concat
    final_kernel<<<NGRAPHS, 128, 0, stream>>>(pooled, batch, lin_W, lin_b,
                                              (float*)d_out, NNODES);
}

// Round 10
// 362.567 us; speedup vs baseline: 2.1610x; 1.1181x over previous
//
#include <hip/hip_runtime.h>
#include <hip/hip_bf16.h>

#define NNODES 50000
#define NEDGES 600000
#define NGRAPHS 512
#define BN_EPS 1e-5f

typedef short bf16x8 __attribute__((ext_vector_type(8)));
typedef float f32x4 __attribute__((ext_vector_type(4)));

// split fp32 -> hi/lo bf16 (RNE); hi+lo carries ~16 mantissa bits (weights only)
__device__ __forceinline__ void bf_split(float x, ushort& h, ushort& l) {
    __hip_bfloat16 bh = __float2bfloat16(x);
    float r = x - __bfloat162float(bh);
    __hip_bfloat16 bl = __float2bfloat16(r);
    h = __builtin_bit_cast(ushort, bh);
    l = __builtin_bit_cast(ushort, bl);
}
__device__ __forceinline__ ushort f2b(float x) {
    return __builtin_bit_cast(ushort, __float2bfloat16(x));
}
__device__ __forceinline__ float b2f(ushort u) {
    union { uint i; float f; } c; c.i = ((uint)u) << 16; return c.f;
}
// bf16 pair unpack from a packed uint: lo = shift, hi = mask (1 VALU each)
__device__ __forceinline__ float blo(uint u) {
    union { uint i; float f; } c; c.i = u << 16; return c.f;
}
__device__ __forceinline__ float bhi(uint u) {
    union { uint i; float f; } c; c.i = u & 0xffff0000u; return c.f;
}

// ------------------------------------------------------------------- prep
// One dispatch: x->bf16 (blocks 0..3124), zero pooled (3125..3316), hist
// over edges (3317..5660; counts pre-zeroed via hipMemsetAsync), wsplit 6
// matrices in MFMA-FRAGMENT ORDER (5661..5756), row_ptr[N] init.
__global__ __launch_bounds__(256) void prep_kernel(
    const float* __restrict__ x, ushort* __restrict__ xh,
    float* __restrict__ pooled, const int* __restrict__ dst,
    int* __restrict__ counts, int* __restrict__ row_ptr,
    const float* W0, const float* W1, const float* W2, const float* W3,
    const float* W4, const float* W5, ushort* __restrict__ hi, ushort* __restrict__ lo) {
    int b = blockIdx.x, t = threadIdx.x;
    if (b < 3125) {                                 // x: 6.4M floats -> bf16
        int f4 = b * 512 + t * 2;
        float4 a0 = ((const float4*)x)[f4];
        float4 a1 = ((const float4*)x)[f4 + 1];
        ushort4 u0 = {f2b(a0.x), f2b(a0.y), f2b(a0.z), f2b(a0.w)};
        ushort4 u1 = {f2b(a1.x), f2b(a1.y), f2b(a1.z), f2b(a1.w)};
        int e0 = f4 * 4;
        *(ushort4*)(xh + e0) = u0;
        *(ushort4*)(xh + e0 + 4) = u1;
        if (b == 0 && t == 0) row_ptr[NNODES] = NEDGES;
    } else if (b < 3317) {                          // pooled: 512*384 floats
        ((float4*)pooled)[(b - 3125) * 256 + t] = make_float4(0.f, 0.f, 0.f, 0.f);
    } else if (b < 5661) {                          // hist: 600000 edges
        int i = (b - 3317) * 256 + t;
        if (i < NEDGES) atomicAdd(&counts[dst[i]], 1);
    } else {                                        // wsplit: 96 blocks
        int wb = b - 5661;
        const float* Ws[6] = {W0, W1, W2, W3, W4, W5};
        const float* W = Ws[wb >> 4];
        ushort* h = hi + (size_t)(wb >> 4) * 16384;
        ushort* l = lo + (size_t)(wb >> 4) * 16384;
        int chunk = wb & 15;
#pragma unroll
        for (int i = 0; i < 4; i++) {
            int idx = chunk * 1024 + i * 256 + t;   // 0..16383 frag-order slot
            int j    = idx & 7;
            int lane = (idx >> 3) & 63;
            int nt   = (idx >> 9) & 7;
            int kb   = (idx >> 12) & 3;
            int k = kb * 32 + ((lane >> 4) << 3) + j;
            int n = nt * 16 + (lane & 15);
            ushort hh, ll;
            bf_split(W[k * 128 + n], hh, ll);
            h[idx] = hh;
            l[idx] = ll;
        }
    }
}

// ------------------------------------------------- fused scan (scan1+scan3)
// Block b: base = sum(counts[0..b*256)) via thread-parallel re-reduction
// (identical integer value to the partials route), then the exact scan3
// intra-chunk exclusive scan. One dispatch instead of two.
__global__ __launch_bounds__(256) void scan_kernel(const int* __restrict__ counts,
                                                   int* __restrict__ row_ptr,
                                                   int* __restrict__ cursor, int n) {
    __shared__ int s[256];
    __shared__ int base_sh;
    int t = threadIdx.x;
    int start = blockIdx.x * 256;
    int partial = 0;
    for (int i = t; i < start; i += 256) partial += counts[i];
    s[t] = partial;
    __syncthreads();
    for (int off = 128; off > 0; off >>= 1) {
        if (t < off) s[t] += s[t + off];
        __syncthreads();
    }
    if (t == 0) base_sh = s[0];
    __syncthreads();
    int base = base_sh;
    int i = start + t;
    int v = (i < n) ? counts[i] : 0;
    __syncthreads();
    s[t] = v;
    __syncthreads();
    for (int off = 1; off < 256; off <<= 1) {
        int nv = (t >= off) ? s[t - off] : 0;
        __syncthreads();
        s[t] += nv;
        __syncthreads();
    }
    if (i < n) {
        int ex = base + s[t] - v;   // exclusive
        row_ptr[i] = ex;
        cursor[i] = ex;
    }
}

__global__ __launch_bounds__(256) void scatter_kernel(const int* __restrict__ src,
                                                      const int* __restrict__ dst,
                                                      int* __restrict__ cursor,
                                                      int* __restrict__ esrc, int E) {
    int i = blockIdx.x * 256 + threadIdx.x;
    if (i < E) {
        int p = atomicAdd(&cursor[dst[i]], 1);
        esrc[p] = src[i];
    }
}

// ------------------------------------------------------------- aggregation
// R4-proven: 4 nodes/wave, 16 lanes x 8 ch (uint4 = 16B/lane). Per-channel
// 8/2/1 pairwise-tree accumulation. Fabric-floor-bound (~35us/layer; R4/R5
// probes showed issue-rate and in-flight-bytes changes are both null).
// Standalone deep grid (3125 blocks = 12500 waves) is REQUIRED: fusing into
// the 782-block mlp grid regressed (R3 73us, R9 62us vs split ~50us/layer).
__global__ __launch_bounds__(256) void agg_kernel(
    const ushort* __restrict__ phi,
    const int* __restrict__ rp, const int* __restrict__ esrc,
    ushort* __restrict__ ohi, int n) {
    int wid  = (blockIdx.x * 256 + threadIdx.x) >> 6;
    int lane = threadIdx.x & 63;
    int node = wid * 4 + (lane >> 4);
    int q = lane & 15;                   // 16B granule: channels q*8..q*8+7
    if (node >= n) return;
    const uint4* xv = (const uint4*)phi; // row = 16 granules of 16B
    uint4 s0 = xv[(size_t)node * 16 + q];
    float acc[8];
    acc[0] = blo(s0.x); acc[1] = bhi(s0.x);
    acc[2] = blo(s0.y); acc[3] = bhi(s0.y);
    acc[4] = blo(s0.z); acc[5] = bhi(s0.z);
    acc[6] = blo(s0.w); acc[7] = bhi(s0.w);
    int e = rp[node], end = rp[node + 1];
    for (; e + 8 <= end; e += 8) {
        int i0 = esrc[e],     i1 = esrc[e + 1], i2 = esrc[e + 2], i3 = esrc[e + 3];
        int i4 = esrc[e + 4], i5 = esrc[e + 5], i6 = esrc[e + 6], i7 = esrc[e + 7];
        uint4 v0 = xv[(size_t)i0 * 16 + q];
        uint4 v1 = xv[(size_t)i1 * 16 + q];
        uint4 v2 = xv[(size_t)i2 * 16 + q];
        uint4 v3 = xv[(size_t)i3 * 16 + q];
        uint4 v4 = xv[(size_t)i4 * 16 + q];
        uint4 v5 = xv[(size_t)i5 * 16 + q];
        uint4 v6 = xv[(size_t)i6 * 16 + q];
        uint4 v7 = xv[(size_t)i7 * 16 + q];
        acc[0] += ((blo(v0.x) + blo(v1.x)) + (blo(v2.x) + blo(v3.x))) +
                  ((blo(v4.x) + blo(v5.x)) + (blo(v6.x) + blo(v7.x)));
        acc[1] += ((bhi(v0.x) + bhi(v1.x)) + (bhi(v2.x) + bhi(v3.x))) +
                  ((bhi(v4.x) + bhi(v5.x)) + (bhi(v6.x) + bhi(v7.x)));
        acc[2] += ((blo(v0.y) + blo(v1.y)) + (blo(v2.y) + blo(v3.y))) +
                  ((blo(v4.y) + blo(v5.y)) + (blo(v6.y) + blo(v7.y)));
        acc[3] += ((bhi(v0.y) + bhi(v1.y)) + (bhi(v2.y) + bhi(v3.y))) +
                  ((bhi(v4.y) + bhi(v5.y)) + (bhi(v6.y) + bhi(v7.y)));
        acc[4] += ((blo(v0.z) + blo(v1.z)) + (blo(v2.z) + blo(v3.z))) +
                  ((blo(v4.z) + blo(v5.z)) + (blo(v6.z) + blo(v7.z)));
        acc[5] += ((bhi(v0.z) + bhi(v1.z)) + (bhi(v2.z) + bhi(v3.z))) +
                  ((bhi(v4.z) + bhi(v5.z)) + (bhi(v6.z) + bhi(v7.z)));
        acc[6] += ((blo(v0.w) + blo(v1.w)) + (blo(v2.w) + blo(v3.w))) +
                  ((blo(v4.w) + blo(v5.w)) + (blo(v6.w) + blo(v7.w)));
        acc[7] += ((bhi(v0.w) + bhi(v1.w)) + (bhi(v2.w) + bhi(v3.w))) +
                  ((bhi(v4.w) + bhi(v5.w)) + (bhi(v6.w) + bhi(v7.w)));
    }
    for (; e + 2 <= end; e += 2) {
        int i0 = esrc[e], i1 = esrc[e + 1];
        uint4 v0 = xv[(size_t)i0 * 16 + q];
        uint4 v1 = xv[(size_t)i1 * 16 + q];
        acc[0] += blo(v0.x) + blo(v1.x); acc[1] += bhi(v0.x) + bhi(v1.x);
        acc[2] += blo(v0.y) + blo(v1.y); acc[3] += bhi(v0.y) + bhi(v1.y);
        acc[4] += blo(v0.z) + blo(v1.z); acc[5] += bhi(v0.z) + bhi(v1.z);
        acc[6] += blo(v0.w) + blo(v1.w); acc[7] += bhi(v0.w) + bhi(v1.w);
    }
    for (; e < end; e++) {
        uint4 v = xv[(size_t)esrc[e] * 16 + q];
        acc[0] += blo(v.x); acc[1] += bhi(v.x);
        acc[2] += blo(v.y); acc[3] += bhi(v.y);
        acc[4] += blo(v.z); acc[5] += bhi(v.z);
        acc[6] += blo(v.w); acc[7] += bhi(v.w);
    }
    uint4 o;
    o.x = (uint)f2b(acc[0]) | ((uint)f2b(acc[1]) << 16);
    o.y = (uint)f2b(acc[2]) | ((uint)f2b(acc[3]) << 16);
    o.z = (uint)f2b(acc[4]) | ((uint)f2b(acc[5]) << 16);
    o.w = (uint)f2b(acc[6]) | ((uint)f2b(acc[7]) << 16);
    *(uint4*)(ohi + (size_t)node * 128 + q * 8) = o;
}

// --------------------------------------------------------------- fused MLP
// C = act( BN_ReLU( A@W1 ) @ W2 ), 64-row tile x 128 threads (2 waves).
// PER-WAVE SHAPE UNCHANGED from proven R14: 64x64 wave tile, 4x4 frags,
// 32 MFMA/kb. W planes stored in MFMA-fragment order -> each bh/bl load is
// one coalesced contiguous 1KB wave transaction. Fused mean-pool epilogue.
template <bool RELU_OUT, bool WRITE_PLANES>
__global__ __launch_bounds__(128) void mlp_kernel(
    const ushort* __restrict__ Ah,
    const ushort* __restrict__ W1hi, const ushort* __restrict__ W1lo,
    const ushort* __restrict__ W2hi, const ushort* __restrict__ W2lo,
    const float* __restrict__ b1, const float* __restrict__ gm,
    const float* __restrict__ bt, const float* __restrict__ rm,
    const float* __restrict__ rv, const float* __restrict__ b2,
    ushort* __restrict__ Ch,
    const int* __restrict__ batch, float* __restrict__ pooled, int poff, int M) {
    __shared__ __align__(16) ushort smem[64 * 136];   // 17408 B
    __shared__ int bsm[64];
    // A dbuf: smem[buf*4096 + m*32 + k]  (8192 ushorts, fits in smem)
    // H / P:  smem[row*136 + col]
    const int t = threadIdx.x;            // 0..127
    const int lane = t & 63;
    const int wv = t >> 6;                // col half
    const int row0 = blockIdx.x * 64;
    const int g = lane >> 4, c = lane & 15;

    if (t < 64) bsm[t] = (row0 + t < M) ? batch[row0 + t] : -1;

    // staging: 256 16B-segs per kb; thread owns segs t and t+128
    const int m0 = t >> 2, k80 = (t & 3) * 8;
    const int m1 = m0 + 32;
    int r0 = row0 + m0; if (r0 >= M) r0 = M - 1;
    int r1 = row0 + m1; if (r1 >= M) r1 = M - 1;
    const size_t ga0 = (size_t)r0 * 128 + k80;
    const size_t ga1 = (size_t)r1 * 128 + k80;
    const int la0 = m0 * 32 + k80, la1 = m1 * 32 + k80;

    f32x4 acc[4][4];
#pragma unroll
    for (int i = 0; i < 4; i++)
#pragma unroll
        for (int j = 0; j < 4; j++) acc[i][j] = (f32x4){0.f, 0.f, 0.f, 0.f};

    uint4 ph0 = *(const uint4*)(Ah + ga0);
    uint4 ph1 = *(const uint4*)(Ah + ga1);
    *(uint4*)&smem[la0] = ph0;
    *(uint4*)&smem[la1] = ph1;
    __syncthreads();

    // ---------------- phase 1: A @ W1 (2 terms)
    int cur = 0;
    for (int kb = 0; kb < 4; kb++) {
        bf16x8 bh[4], bl[4];
#pragma unroll
        for (int ct = 0; ct < 4; ct++) {
            const size_t wo = (((size_t)kb * 8 + (wv * 4 + ct)) * 64 + lane) * 8;
            bh[ct] = *(const bf16x8*)(W1hi + wo);
            bl[ct] = *(const bf16x8*)(W1lo + wo);
        }
        if (kb < 3) {
            const size_t o = (size_t)(kb + 1) * 32;
            ph0 = *(const uint4*)(Ah + ga0 + o);
            ph1 = *(const uint4*)(Ah + ga1 + o);
        }
        bf16x8 ah[4];
#pragma unroll
        for (int rt = 0; rt < 4; rt++) {
            int off = cur * 4096 + (rt * 16 + c) * 32 + g * 8;
            ah[rt] = *(bf16x8*)&smem[off];
        }
#pragma unroll
        for (int rt = 0; rt < 4; rt++)
#pragma unroll
            for (int ct = 0; ct < 4; ct++) {
                acc[rt][ct] = __builtin_amdgcn_mfma_f32_16x16x32_bf16(ah[rt], bh[ct], acc[rt][ct], 0, 0, 0);
                acc[rt][ct] = __builtin_amdgcn_mfma_f32_16x16x32_bf16(ah[rt], bl[ct], acc[rt][ct], 0, 0, 0);
            }
        if (kb < 3) {
            *(uint4*)&smem[(cur ^ 1) * 4096 + la0] = ph0;
            *(uint4*)&smem[(cur ^ 1) * 4096 + la1] = ph1;
        }
        __syncthreads();   // final iter: all A reads done -> H may overwrite
        cur ^= 1;
    }

    // ---------------- BN + ReLU -> H (bf16)
    {
        float cs[4], ca[4];
#pragma unroll
        for (int ct = 0; ct < 4; ct++) {
            int n = wv * 64 + ct * 16 + c;
            float s = gm[n] * rsqrtf(rv[n] + BN_EPS);
            cs[ct] = s;
            ca[ct] = (b1[n] - rm[n]) * s + bt[n];
        }
#pragma unroll
        for (int rt = 0; rt < 4; rt++)
#pragma unroll
            for (int r = 0; r < 4; r++) {
                int row = rt * 16 + g * 4 + r;
#pragma unroll
                for (int ct = 0; ct < 4; ct++) {
                    int col = wv * 64 + ct * 16 + c;
                    float v = fmaxf(acc[rt][ct][r] * cs[ct] + ca[ct], 0.f);
                    smem[row * 136 + col] = f2b(v);
                }
            }
    }
    __syncthreads();

    // ---------------- phase 2: H @ W2 (2 terms)
#pragma unroll
    for (int i = 0; i < 4; i++)
#pragma unroll
        for (int j = 0; j < 4; j++) acc[i][j] = (f32x4){0.f, 0.f, 0.f, 0.f};

    for (int kb = 0; kb < 4; kb++) {
        bf16x8 bh[4], bl[4];
#pragma unroll
        for (int ct = 0; ct < 4; ct++) {
            const size_t wo = (((size_t)kb * 8 + (wv * 4 + ct)) * 64 + lane) * 8;
            bh[ct] = *(const bf16x8*)(W2hi + wo);
            bl[ct] = *(const bf16x8*)(W2lo + wo);
        }
        bf16x8 ah[4];
#pragma unroll
        for (int rt = 0; rt < 4; rt++) {
            int off = (rt * 16 + c) * 136 + kb * 32 + g * 8;
            ah[rt] = *(bf16x8*)&smem[off];
        }
#pragma unroll
        for (int rt = 0; rt < 4; rt++)
#pragma unroll
            for (int ct = 0; ct < 4; ct++) {
                acc[rt][ct] = __builtin_amdgcn_mfma_f32_16x16x32_bf16(ah[rt], bh[ct], acc[rt][ct], 0, 0, 0);
                acc[rt][ct] = __builtin_amdgcn_mfma_f32_16x16x32_bf16(ah[rt], bl[ct], acc[rt][ct], 0, 0, 0);
            }
    }
    __syncthreads();   // all H reads done -> P may overwrite smem

    // ---------------- epilogue: +b2 (,ReLU) -> bf16 plane + LDS P (bf16)
    {
        float ca2[4];
#pragma unroll
        for (int ct = 0; ct < 4; ct++) ca2[ct] = b2[wv * 64 + ct * 16 + c];
#pragma unroll
        for (int rt = 0; rt < 4; rt++)
#pragma unroll
            for (int r = 0; r < 4; r++) {
                int rl = rt * 16 + g * 4 + r;
                int row = row0 + rl;
                bool valid = row < M;
#pragma unroll
                for (int ct = 0; ct < 4; ct++) {
                    int col = wv * 64 + ct * 16 + c;
                    float v = acc[rt][ct][r] + ca2[ct];
                    if (RELU_OUT) v = fmaxf(v, 0.f);
                    ushort hh = f2b(valid ? v : 0.f);
                    smem[rl * 136 + col] = hh;
                    if (WRITE_PLANES && valid) Ch[(size_t)row * 128 + col] = hh;
                }
            }
    }
    __syncthreads();

    // ---------------- fused mean-pool contribution (batch is sorted)
    {
        int col = t;              // 0..127
        int gcur = bsm[0];
        float accp = 0.f;
#pragma unroll 8
        for (int r = 0; r < 64; r++) {
            int gg = bsm[r];
            if (gg != gcur) {     // block-uniform branch (sorted batch)
                if (gcur >= 0) atomicAdd(&pooled[gcur * 384 + poff + col], accp);
                accp = 0.f;
                gcur = gg;
            }
            accp += b2f(smem[r * 136 + col]);
        }
        if (gcur >= 0) atomicAdd(&pooled[gcur * 384 + poff + col], accp);
    }
}

// ------------------------------------------------------------------- final
__global__ __launch_bounds__(128) void final_kernel(const float* __restrict__ pooled,
                                                    const int* __restrict__ batch,
                                                    const float* __restrict__ W,
                                                    const float* __restrict__ b,
                                                    float* __restrict__ out, int n) {
    __shared__ float ps[384];
    int gph = blockIdx.x, t = threadIdx.x;
    int lo1 = 0, hi1 = n;
    while (lo1 < hi1) { int mid = (lo1 + hi1) >> 1; if (batch[mid] < gph) lo1 = mid + 1; else hi1 = mid; }
    int start = lo1;
    int lo2 = start, hi2 = n;
    while (lo2 < hi2) { int mid = (lo2 + hi2) >> 1; if (batch[mid] < gph + 1) lo2 = mid + 1; else hi2 = mid; }
    int cnt = lo2 - start;
    float inv = 1.f / (float)(cnt > 0 ? cnt : 1);
    for (int i = t; i < 384; i += 128) ps[i] = pooled[gph * 384 + i] * inv;
    __syncthreads();
    float acc = b[t];
#pragma unroll 8
    for (int k = 0; k < 384; k++) acc += ps[k] * W[k * 128 + t];
    out[gph * 128 + t] = acc;
}

// ------------------------------------------------------------------ launch
extern "C" void kernel_launch(void* const* d_in, const int* in_sizes, int n_in,
                              void* d_out, int out_size, void* d_ws, size_t ws_size,
                              hipStream_t stream) {
    const float* x     = (const float*)d_in[0];
    const int*   edge  = (const int*)d_in[1];
    const int*   batch = (const int*)d_in[2];
    const float* p[32];
    for (int i = 0; i < n_in && i < 32; i++) p[i] = (const float*)d_in[i];
    const float* lin_W = p[27];
    const float* lin_b = p[28];

    char* w = (char*)d_ws;
    auto alloc = [&](size_t bytes) { void* r = (void*)w; w += (bytes + 255) & ~(size_t)255; return r; };
    const size_t PL = (size_t)NNODES * 128;
    ushort* thi   = (ushort*)alloc(PL * 2);   // agg out plane
    ushort* xh0   = (ushort*)alloc(PL * 2);   // bf16(x); dead after agg L1
    ushort* p1h   = (ushort*)alloc(PL * 2);
    ushort* p2h   = xh0;                      // alias: xh0 dead before mlp L2 writes
    float* pooled = (float*)alloc((size_t)NGRAPHS * 384 * 4);
    int* counts   = (int*)alloc((size_t)NNODES * 4);
    int* cursor   = (int*)alloc((size_t)NNODES * 4);
    int* row_ptr  = (int*)alloc((size_t)(NNODES + 1) * 4);
    int* esrc     = (int*)alloc((size_t)NEDGES * 4);
    ushort* wt_hi = (ushort*)alloc((size_t)6 * 16384 * 2);
    ushort* wt_lo = (ushort*)alloc((size_t)6 * 16384 * 2);

    const int* src = edge;
    const int* dst = edge + NEDGES;

    // --- zero counts (stream-ordered), then prep incl. hist + frag wsplit
    hipMemsetAsync(counts, 0, (size_t)NNODES * 4, stream);
    prep_kernel<<<5757, 256, 0, stream>>>(x, xh0, pooled, dst, counts, row_ptr,
                                          p[3], p[9], p[11], p[17], p[19], p[25],
                                          wt_hi, wt_lo);

    // --- CSR build: 2 dispatches (fused scan, then scatter)
    int nb = (NNODES + 255) / 256;  // 196
    scan_kernel<<<nb, 256, 0, stream>>>(counts, row_ptr, cursor, NNODES);
    scatter_kernel<<<(NEDGES + 255) / 256, 256, 0, stream>>>(src, dst, cursor, esrc, NEDGES);

    // --- 3 GIN layers (split agg + mlp; mlp fuses the mean-pool contribution)
    int mlp_grid = (NNODES + 63) / 64;              // 782
    int agg_grid = (NNODES / 4 * 64 + 255) / 256;   // 3125

    // layer 1 (self from bf16 plane — same rounding class as neighbors)
    agg_kernel<<<agg_grid, 256, 0, stream>>>(xh0, row_ptr, esrc, thi, NNODES);
    mlp_kernel<true, true><<<mlp_grid, 128, 0, stream>>>(thi,
        wt_hi + 0 * 16384, wt_lo + 0 * 16384, wt_hi + 1 * 16384, wt_lo + 1 * 16384,
        p[4], p[5], p[6], p[7], p[8], p[10], p1h, batch, pooled, 0, NNODES);
    // layer 2
    agg_kernel<<<agg_grid, 256, 0, stream>>>(p1h, row_ptr, esrc, thi, NNODES);
    mlp_kernel<true, true><<<mlp_grid, 128, 0, stream>>>(thi,
        wt_hi + 2 * 16384, wt_lo + 2 * 16384, wt_hi + 3 * 16384, wt_lo + 3 * 16384,
        p[12], p[13], p[14], p[15], p[16], p[18], p2h, batch, pooled, 128, NNODES);
    // layer 3 (no relu, no plane writes — pool-only output)
    agg_kernel<<<agg_grid, 256, 0, stream>>>(p2h, row_ptr, esrc, thi, NNODES);
    mlp_kernel<false, false><<<mlp_grid, 128, 0, stream>>>(thi,
        wt_hi + 4 * 16384, wt_lo + 4 * 16384, wt_hi + 5 * 16384, wt_lo + 5 * 16384,
        p[20], p[21], p[22], p[23], p[24], p[26], nullptr, batch, pooled, 256, NNODES);

    // --- final linear on mean-pooled JK-concat
    final_kernel<<<NGRAPHS, 128, 0, stream>>>(pooled, batch, lin_W, lin_b,
                                              (float*)d_out, NNODES);
}

// Round 11
// 341.476 us; speedup vs baseline: 2.2945x; 1.0618x over previous
//
#include <hip/hip_runtime.h>
#include <hip/hip_bf16.h>

#define NNODES 50000
#define NEDGES 600000
#define NGRAPHS 512
#define BN_EPS 1e-5f

typedef short bf16x8 __attribute__((ext_vector_type(8)));
typedef float f32x4 __attribute__((ext_vector_type(4)));

// split fp32 -> hi/lo bf16 (RNE); hi+lo carries ~16 mantissa bits (weights only)
__device__ __forceinline__ void bf_split(float x, ushort& h, ushort& l) {
    __hip_bfloat16 bh = __float2bfloat16(x);
    float r = x - __bfloat162float(bh);
    __hip_bfloat16 bl = __float2bfloat16(r);
    h = __builtin_bit_cast(ushort, bh);
    l = __builtin_bit_cast(ushort, bl);
}
__device__ __forceinline__ ushort f2b(float x) {
    return __builtin_bit_cast(ushort, __float2bfloat16(x));
}
__device__ __forceinline__ float b2f(ushort u) {
    union { uint i; float f; } c; c.i = ((uint)u) << 16; return c.f;
}
// bf16 pair unpack from a packed uint: lo = shift, hi = mask (1 VALU each)
__device__ __forceinline__ float blo(uint u) {
    union { uint i; float f; } c; c.i = u << 16; return c.f;
}
__device__ __forceinline__ float bhi(uint u) {
    union { uint i; float f; } c; c.i = u & 0xffff0000u; return c.f;
}

// ------------------------------------------------------------------- prep
// One dispatch: x->bf16 (blocks 0..3124), zero pooled (3125..3316), hist
// over edges (3317..5660; counts pre-zeroed via hipMemsetAsync), wsplit 6
// matrices in MFMA-FRAGMENT ORDER (5661..5756), row_ptr[N] init.
__global__ __launch_bounds__(256) void prep_kernel(
    const float* __restrict__ x, ushort* __restrict__ xh,
    float* __restrict__ pooled, const int* __restrict__ dst,
    int* __restrict__ counts, int* __restrict__ row_ptr,
    const float* W0, const float* W1, const float* W2, const float* W3,
    const float* W4, const float* W5, ushort* __restrict__ hi, ushort* __restrict__ lo) {
    int b = blockIdx.x, t = threadIdx.x;
    if (b < 3125) {                                 // x: 6.4M floats -> bf16
        int f4 = b * 512 + t * 2;
        float4 a0 = ((const float4*)x)[f4];
        float4 a1 = ((const float4*)x)[f4 + 1];
        ushort4 u0 = {f2b(a0.x), f2b(a0.y), f2b(a0.z), f2b(a0.w)};
        ushort4 u1 = {f2b(a1.x), f2b(a1.y), f2b(a1.z), f2b(a1.w)};
        int e0 = f4 * 4;
        *(ushort4*)(xh + e0) = u0;
        *(ushort4*)(xh + e0 + 4) = u1;
        if (b == 0 && t == 0) row_ptr[NNODES] = NEDGES;
    } else if (b < 3317) {                          // pooled: 512*384 floats
        ((float4*)pooled)[(b - 3125) * 256 + t] = make_float4(0.f, 0.f, 0.f, 0.f);
    } else if (b < 5661) {                          // hist: 600000 edges
        int i = (b - 3317) * 256 + t;
        if (i < NEDGES) atomicAdd(&counts[dst[i]], 1);
    } else {                                        // wsplit: 96 blocks
        int wb = b - 5661;
        const float* Ws[6] = {W0, W1, W2, W3, W4, W5};
        const float* W = Ws[wb >> 4];
        ushort* h = hi + (size_t)(wb >> 4) * 16384;
        ushort* l = lo + (size_t)(wb >> 4) * 16384;
        int chunk = wb & 15;
#pragma unroll
        for (int i = 0; i < 4; i++) {
            int idx = chunk * 1024 + i * 256 + t;   // 0..16383 frag-order slot
            int j    = idx & 7;
            int lane = (idx >> 3) & 63;
            int nt   = (idx >> 9) & 7;
            int kb   = (idx >> 12) & 3;
            int k = kb * 32 + ((lane >> 4) << 3) + j;
            int n = nt * 16 + (lane & 15);
            ushort hh, ll;
            bf_split(W[k * 128 + n], hh, ll);
            h[idx] = hh;
            l[idx] = ll;
        }
    }
}

// ---------------------------------------------------------------- CSR build
__global__ __launch_bounds__(256) void scan1_kernel(const int* __restrict__ counts,
                                                    int* __restrict__ partials, int n) {
    __shared__ int s[256];
    int i = blockIdx.x * 256 + threadIdx.x;
    int v = (i < n) ? counts[i] : 0;
    s[threadIdx.x] = v;
    __syncthreads();
    for (int off = 128; off > 0; off >>= 1) {
        if (threadIdx.x < off) s[threadIdx.x] += s[threadIdx.x + off];
        __syncthreads();
    }
    if (threadIdx.x == 0) partials[blockIdx.x] = s[0];
}

// scan3 with inline base reduction (no scan2 dispatch), nb<=256
__global__ __launch_bounds__(256) void scan3_kernel(const int* __restrict__ counts,
                                                    const int* __restrict__ partials,
                                                    int* __restrict__ row_ptr,
                                                    int* __restrict__ cursor, int n, int nb) {
    __shared__ int s[256];
    __shared__ int base_sh;
    int t = threadIdx.x;
    int pv = (t < (int)blockIdx.x && t < nb) ? partials[t] : 0;
    s[t] = pv;
    __syncthreads();
    for (int off = 128; off > 0; off >>= 1) {
        if (t < off) s[t] += s[t + off];
        __syncthreads();
    }
    if (t == 0) base_sh = s[0];
    __syncthreads();
    int base = base_sh;
    int i = blockIdx.x * 256 + t;
    int v = (i < n) ? counts[i] : 0;
    __syncthreads();
    s[t] = v;
    __syncthreads();
    for (int off = 1; off < 256; off <<= 1) {
        int nv = (t >= off) ? s[t - off] : 0;
        __syncthreads();
        s[t] += nv;
        __syncthreads();
    }
    if (i < n) {
        int ex = base + s[t] - v;   // exclusive
        row_ptr[i] = ex;
        cursor[i] = ex;
    }
}

__global__ __launch_bounds__(256) void scatter_kernel(const int* __restrict__ src,
                                                      const int* __restrict__ dst,
                                                      int* __restrict__ cursor,
                                                      int* __restrict__ esrc, int E) {
    int i = blockIdx.x * 256 + threadIdx.x;
    if (i < E) {
        int p = atomicAdd(&cursor[dst[i]], 1);
        esrc[p] = src[i];
    }
}

// ------------------------------------------------------------- aggregation
// R4-proven: 4 nodes/wave, 16 lanes x 8 ch (uint4 = 16B/lane). Per-channel
// 8/2/1 pairwise-tree accumulation. Fabric-floor-bound (~40us/layer; R4/R5
// probes showed issue-rate and in-flight-bytes changes are both null).
// Standalone deep grid (3125 blocks = 12500 waves) is REQUIRED: fusing into
// the 782-block mlp grid regressed (R3 73us, R9 62us).
__global__ __launch_bounds__(256) void agg_kernel(
    const ushort* __restrict__ phi,
    const int* __restrict__ rp, const int* __restrict__ esrc,
    ushort* __restrict__ ohi, int n) {
    int wid  = (blockIdx.x * 256 + threadIdx.x) >> 6;
    int lane = threadIdx.x & 63;
    int node = wid * 4 + (lane >> 4);
    int q = lane & 15;                   // 16B granule: channels q*8..q*8+7
    if (node >= n) return;
    const uint4* xv = (const uint4*)phi; // row = 16 granules of 16B
    uint4 s0 = xv[(size_t)node * 16 + q];
    float acc[8];
    acc[0] = blo(s0.x); acc[1] = bhi(s0.x);
    acc[2] = blo(s0.y); acc[3] = bhi(s0.y);
    acc[4] = blo(s0.z); acc[5] = bhi(s0.z);
    acc[6] = blo(s0.w); acc[7] = bhi(s0.w);
    int e = rp[node], end = rp[node + 1];
    for (; e + 8 <= end; e += 8) {
        int i0 = esrc[e],     i1 = esrc[e + 1], i2 = esrc[e + 2], i3 = esrc[e + 3];
        int i4 = esrc[e + 4], i5 = esrc[e + 5], i6 = esrc[e + 6], i7 = esrc[e + 7];
        uint4 v0 = xv[(size_t)i0 * 16 + q];
        uint4 v1 = xv[(size_t)i1 * 16 + q];
        uint4 v2 = xv[(size_t)i2 * 16 + q];
        uint4 v3 = xv[(size_t)i3 * 16 + q];
        uint4 v4 = xv[(size_t)i4 * 16 + q];
        uint4 v5 = xv[(size_t)i5 * 16 + q];
        uint4 v6 = xv[(size_t)i6 * 16 + q];
        uint4 v7 = xv[(size_t)i7 * 16 + q];
        acc[0] += ((blo(v0.x) + blo(v1.x)) + (blo(v2.x) + blo(v3.x))) +
                  ((blo(v4.x) + blo(v5.x)) + (blo(v6.x) + blo(v7.x)));
        acc[1] += ((bhi(v0.x) + bhi(v1.x)) + (bhi(v2.x) + bhi(v3.x))) +
                  ((bhi(v4.x) + bhi(v5.x)) + (bhi(v6.x) + bhi(v7.x)));
        acc[2] += ((blo(v0.y) + blo(v1.y)) + (blo(v2.y) + blo(v3.y))) +
                  ((blo(v4.y) + blo(v5.y)) + (blo(v6.y) + blo(v7.y)));
        acc[3] += ((bhi(v0.y) + bhi(v1.y)) + (bhi(v2.y) + bhi(v3.y))) +
                  ((bhi(v4.y) + bhi(v5.y)) + (bhi(v6.y) + bhi(v7.y)));
        acc[4] += ((blo(v0.z) + blo(v1.z)) + (blo(v2.z) + blo(v3.z))) +
                  ((blo(v4.z) + blo(v5.z)) + (blo(v6.z) + blo(v7.z)));
        acc[5] += ((bhi(v0.z) + bhi(v1.z)) + (bhi(v2.z) + bhi(v3.z))) +
                  ((bhi(v4.z) + bhi(v5.z)) + (bhi(v6.z) + bhi(v7.z)));
        acc[6] += ((blo(v0.w) + blo(v1.w)) + (blo(v2.w) + blo(v3.w))) +
                  ((blo(v4.w) + blo(v5.w)) + (blo(v6.w) + blo(v7.w)));
        acc[7] += ((bhi(v0.w) + bhi(v1.w)) + (bhi(v2.w) + bhi(v3.w))) +
                  ((bhi(v4.w) + bhi(v5.w)) + (bhi(v6.w) + bhi(v7.w)));
    }
    for (; e + 2 <= end; e += 2) {
        int i0 = esrc[e], i1 = esrc[e + 1];
        uint4 v0 = xv[(size_t)i0 * 16 + q];
        uint4 v1 = xv[(size_t)i1 * 16 + q];
        acc[0] += blo(v0.x) + blo(v1.x); acc[1] += bhi(v0.x) + bhi(v1.x);
        acc[2] += blo(v0.y) + blo(v1.y); acc[3] += bhi(v0.y) + bhi(v1.y);
        acc[4] += blo(v0.z) + blo(v1.z); acc[5] += bhi(v0.z) + bhi(v1.z);
        acc[6] += blo(v0.w) + blo(v1.w); acc[7] += bhi(v0.w) + bhi(v1.w);
    }
    for (; e < end; e++) {
        uint4 v = xv[(size_t)esrc[e] * 16 + q];
        acc[0] += blo(v.x); acc[1] += bhi(v.x);
        acc[2] += blo(v.y); acc[3] += bhi(v.y);
        acc[4] += blo(v.z); acc[5] += bhi(v.z);
        acc[6] += blo(v.w); acc[7] += bhi(v.w);
    }
    uint4 o;
    o.x = (uint)f2b(acc[0]) | ((uint)f2b(acc[1]) << 16);
    o.y = (uint)f2b(acc[2]) | ((uint)f2b(acc[3]) << 16);
    o.z = (uint)f2b(acc[4]) | ((uint)f2b(acc[5]) << 16);
    o.w = (uint)f2b(acc[6]) | ((uint)f2b(acc[7]) << 16);
    *(uint4*)(ohi + (size_t)node * 128 + q * 8) = o;
}

// --------------------------------------------------------------- fused MLP
// C = act( BN_ReLU( A@W1 ) @ W2 ), 64-row tile x 128 threads (2 waves).
// PER-WAVE SHAPE UNCHANGED from proven R14: 64x64 wave tile, 4x4 frags,
// 32 MFMA/kb. W planes stored in MFMA-fragment order -> each bh/bl load is
// one coalesced contiguous 1KB wave transaction. Fused mean-pool epilogue.
template <bool RELU_OUT, bool WRITE_PLANES>
__global__ __launch_bounds__(128) void mlp_kernel(
    const ushort* __restrict__ Ah,
    const ushort* __restrict__ W1hi, const ushort* __restrict__ W1lo,
    const ushort* __restrict__ W2hi, const ushort* __restrict__ W2lo,
    const float* __restrict__ b1, const float* __restrict__ gm,
    const float* __restrict__ bt, const float* __restrict__ rm,
    const float* __restrict__ rv, const float* __restrict__ b2,
    ushort* __restrict__ Ch,
    const int* __restrict__ batch, float* __restrict__ pooled, int poff, int M) {
    __shared__ __align__(16) ushort smem[64 * 136];   // 17408 B
    __shared__ int bsm[64];
    // A dbuf: smem[buf*4096 + m*32 + k]  (8192 ushorts, fits in smem)
    // H / P:  smem[row*136 + col]
    const int t = threadIdx.x;            // 0..127
    const int lane = t & 63;
    const int wv = t >> 6;                // col half
    const int row0 = blockIdx.x * 64;
    const int g = lane >> 4, c = lane & 15;

    if (t < 64) bsm[t] = (row0 + t < M) ? batch[row0 + t] : -1;

    // staging: 256 16B-segs per kb; thread owns segs t and t+128
    const int m0 = t >> 2, k80 = (t & 3) * 8;
    const int m1 = m0 + 32;
    int r0 = row0 + m0; if (r0 >= M) r0 = M - 1;
    int r1 = row0 + m1; if (r1 >= M) r1 = M - 1;
    const size_t ga0 = (size_t)r0 * 128 + k80;
    const size_t ga1 = (size_t)r1 * 128 + k80;
    const int la0 = m0 * 32 + k80, la1 = m1 * 32 + k80;

    f32x4 acc[4][4];
#pragma unroll
    for (int i = 0; i < 4; i++)
#pragma unroll
        for (int j = 0; j < 4; j++) acc[i][j] = (f32x4){0.f, 0.f, 0.f, 0.f};

    uint4 ph0 = *(const uint4*)(Ah + ga0);
    uint4 ph1 = *(const uint4*)(Ah + ga1);
    *(uint4*)&smem[la0] = ph0;
    *(uint4*)&smem[la1] = ph1;
    __syncthreads();

    // ---------------- phase 1: A @ W1 (2 terms)
    int cur = 0;
    for (int kb = 0; kb < 4; kb++) {
        bf16x8 bh[4], bl[4];
#pragma unroll
        for (int ct = 0; ct < 4; ct++) {
            const size_t wo = (((size_t)kb * 8 + (wv * 4 + ct)) * 64 + lane) * 8;
            bh[ct] = *(const bf16x8*)(W1hi + wo);
            bl[ct] = *(const bf16x8*)(W1lo + wo);
        }
        if (kb < 3) {
            const size_t o = (size_t)(kb + 1) * 32;
            ph0 = *(const uint4*)(Ah + ga0 + o);
            ph1 = *(const uint4*)(Ah + ga1 + o);
        }
        bf16x8 ah[4];
#pragma unroll
        for (int rt = 0; rt < 4; rt++) {
            int off = cur * 4096 + (rt * 16 + c) * 32 + g * 8;
            ah[rt] = *(bf16x8*)&smem[off];
        }
#pragma unroll
        for (int rt = 0; rt < 4; rt++)
#pragma unroll
            for (int ct = 0; ct < 4; ct++) {
                acc[rt][ct] = __builtin_amdgcn_mfma_f32_16x16x32_bf16(ah[rt], bh[ct], acc[rt][ct], 0, 0, 0);
                acc[rt][ct] = __builtin_amdgcn_mfma_f32_16x16x32_bf16(ah[rt], bl[ct], acc[rt][ct], 0, 0, 0);
            }
        if (kb < 3) {
            *(uint4*)&smem[(cur ^ 1) * 4096 + la0] = ph0;
            *(uint4*)&smem[(cur ^ 1) * 4096 + la1] = ph1;
        }
        __syncthreads();   // final iter: all A reads done -> H may overwrite
        cur ^= 1;
    }

    // ---------------- BN + ReLU -> H (bf16)
    {
        float cs[4], ca[4];
#pragma unroll
        for (int ct = 0; ct < 4; ct++) {
            int n = wv * 64 + ct * 16 + c;
            float s = gm[n] * rsqrtf(rv[n] + BN_EPS);
            cs[ct] = s;
            ca[ct] = (b1[n] - rm[n]) * s + bt[n];
        }
#pragma unroll
        for (int rt = 0; rt < 4; rt++)
#pragma unroll
            for (int r = 0; r < 4; r++) {
                int row = rt * 16 + g * 4 + r;
#pragma unroll
                for (int ct = 0; ct < 4; ct++) {
                    int col = wv * 64 + ct * 16 + c;
                    float v = fmaxf(acc[rt][ct][r] * cs[ct] + ca[ct], 0.f);
                    smem[row * 136 + col] = f2b(v);
                }
            }
    }
    __syncthreads();

    // ---------------- phase 2: H @ W2 (2 terms)
#pragma unroll
    for (int i = 0; i < 4; i++)
#pragma unroll
        for (int j = 0; j < 4; j++) acc[i][j] = (f32x4){0.f, 0.f, 0.f, 0.f};

    for (int kb = 0; kb < 4; kb++) {
        bf16x8 bh[4], bl[4];
#pragma unroll
        for (int ct = 0; ct < 4; ct++) {
            const size_t wo = (((size_t)kb * 8 + (wv * 4 + ct)) * 64 + lane) * 8;
            bh[ct] = *(const bf16x8*)(W2hi + wo);
            bl[ct] = *(const bf16x8*)(W2lo + wo);
        }
        bf16x8 ah[4];
#pragma unroll
        for (int rt = 0; rt < 4; rt++) {
            int off = (rt * 16 + c) * 136 + kb * 32 + g * 8;
            ah[rt] = *(bf16x8*)&smem[off];
        }
#pragma unroll
        for (int rt = 0; rt < 4; rt++)
#pragma unroll
            for (int ct = 0; ct < 4; ct++) {
                acc[rt][ct] = __builtin_amdgcn_mfma_f32_16x16x32_bf16(ah[rt], bh[ct], acc[rt][ct], 0, 0, 0);
                acc[rt][ct] = __builtin_amdgcn_mfma_f32_16x16x32_bf16(ah[rt], bl[ct], acc[rt][ct], 0, 0, 0);
            }
    }
    __syncthreads();   // all H reads done -> P may overwrite smem

    // ---------------- epilogue: +b2 (,ReLU) -> bf16 plane + LDS P (bf16)
    {
        float ca2[4];
#pragma unroll
        for (int ct = 0; ct < 4; ct++) ca2[ct] = b2[wv * 64 + ct * 16 + c];
#pragma unroll
        for (int rt = 0; rt < 4; rt++)
#pragma unroll
            for (int r = 0; r < 4; r++) {
                int rl = rt * 16 + g * 4 + r;
                int row = row0 + rl;
                bool valid = row < M;
#pragma unroll
                for (int ct = 0; ct < 4; ct++) {
                    int col = wv * 64 + ct * 16 + c;
                    float v = acc[rt][ct][r] + ca2[ct];
                    if (RELU_OUT) v = fmaxf(v, 0.f);
                    ushort hh = f2b(valid ? v : 0.f);
                    smem[rl * 136 + col] = hh;
                    if (WRITE_PLANES && valid) Ch[(size_t)row * 128 + col] = hh;
                }
            }
    }
    __syncthreads();

    // ---------------- fused mean-pool contribution (batch is sorted)
    {
        int col = t;              // 0..127
        int gcur = bsm[0];
        float accp = 0.f;
#pragma unroll 8
        for (int r = 0; r < 64; r++) {
            int gg = bsm[r];
            if (gg != gcur) {     // block-uniform branch (sorted batch)
                if (gcur >= 0) atomicAdd(&pooled[gcur * 384 + poff + col], accp);
                accp = 0.f;
                gcur = gg;
            }
            accp += b2f(smem[r * 136 + col]);
        }
        if (gcur >= 0) atomicAdd(&pooled[gcur * 384 + poff + col], accp);
    }
}

// ------------------------------------------------------------------- final
__global__ __launch_bounds__(128) void final_kernel(const float* __restrict__ pooled,
                                                    const int* __restrict__ batch,
                                                    const float* __restrict__ W,
                                                    const float* __restrict__ b,
                                                    float* __restrict__ out, int n) {
    __shared__ float ps[384];
    int gph = blockIdx.x, t = threadIdx.x;
    int lo1 = 0, hi1 = n;
    while (lo1 < hi1) { int mid = (lo1 + hi1) >> 1; if (batch[mid] < gph) lo1 = mid + 1; else hi1 = mid; }
    int start = lo1;
    int lo2 = start, hi2 = n;
    while (lo2 < hi2) { int mid = (lo2 + hi2) >> 1; if (batch[mid] < gph + 1) lo2 = mid + 1; else hi2 = mid; }
    int cnt = lo2 - start;
    float inv = 1.f / (float)(cnt > 0 ? cnt : 1);
    for (int i = t; i < 384; i += 128) ps[i] = pooled[gph * 384 + i] * inv;
    __syncthreads();
    float acc = b[t];
#pragma unroll 8
    for (int k = 0; k < 384; k++) acc += ps[k] * W[k * 128 + t];
    out[gph * 128 + t] = acc;
}

// ------------------------------------------------------------------ launch
extern "C" void kernel_launch(void* const* d_in, const int* in_sizes, int n_in,
                              void* d_out, int out_size, void* d_ws, size_t ws_size,
                              hipStream_t stream) {
    const float* x     = (const float*)d_in[0];
    const int*   edge  = (const int*)d_in[1];
    const int*   batch = (const int*)d_in[2];
    const float* p[32];
    for (int i = 0; i < n_in && i < 32; i++) p[i] = (const float*)d_in[i];
    const float* lin_W = p[27];
    const float* lin_b = p[28];

    char* w = (char*)d_ws;
    auto alloc = [&](size_t bytes) { void* r = (void*)w; w += (bytes + 255) & ~(size_t)255; return r; };
    const size_t PL = (size_t)NNODES * 128;
    ushort* thi   = (ushort*)alloc(PL * 2);   // agg out plane
    ushort* xh0   = (ushort*)alloc(PL * 2);   // bf16(x); dead after agg L1
    ushort* p1h   = (ushort*)alloc(PL * 2);
    ushort* p2h   = xh0;                      // alias: xh0 dead before mlp L2 writes
    float* pooled = (float*)alloc((size_t)NGRAPHS * 384 * 4);
    int* counts   = (int*)alloc((size_t)NNODES * 4);
    int* cursor   = (int*)alloc((size_t)NNODES * 4);
    int* row_ptr  = (int*)alloc((size_t)(NNODES + 1) * 4);
    int* esrc     = (int*)alloc((size_t)NEDGES * 4);
    int* partials = (int*)alloc(256 * 4);
    ushort* wt_hi = (ushort*)alloc((size_t)6 * 16384 * 2);
    ushort* wt_lo = (ushort*)alloc((size_t)6 * 16384 * 2);

    const int* src = edge;
    const int* dst = edge + NEDGES;

    // --- zero counts (stream-ordered), then prep incl. hist + frag wsplit
    hipMemsetAsync(counts, 0, (size_t)NNODES * 4, stream);
    prep_kernel<<<5757, 256, 0, stream>>>(x, xh0, pooled, dst, counts, row_ptr,
                                          p[3], p[9], p[11], p[17], p[19], p[25],
                                          wt_hi, wt_lo);

    // --- CSR build: 3 dispatches (parallel scans; fused single-scan
    // regressed +22us via its dependent base-sum latency chain — R10)
    int nb = (NNODES + 255) / 256;  // 196
    scan1_kernel<<<nb, 256, 0, stream>>>(counts, partials, NNODES);
    scan3_kernel<<<nb, 256, 0, stream>>>(counts, partials, row_ptr, cursor, NNODES, nb);
    scatter_kernel<<<(NEDGES + 255) / 256, 256, 0, stream>>>(src, dst, cursor, esrc, NEDGES);

    // --- 3 GIN layers (split agg + mlp; mlp fuses the mean-pool contribution)
    int mlp_grid = (NNODES + 63) / 64;              // 782
    int agg_grid = (NNODES / 4 * 64 + 255) / 256;   // 3125

    // layer 1 (self from bf16 plane — same rounding class as neighbors)
    agg_kernel<<<agg_grid, 256, 0, stream>>>(xh0, row_ptr, esrc, thi, NNODES);
    mlp_kernel<true, true><<<mlp_grid, 128, 0, stream>>>(thi,
        wt_hi + 0 * 16384, wt_lo + 0 * 16384, wt_hi + 1 * 16384, wt_lo + 1 * 16384,
        p[4], p[5], p[6], p[7], p[8], p[10], p1h, batch, pooled, 0, NNODES);
    // layer 2
    agg_kernel<<<agg_grid, 256, 0, stream>>>(p1h, row_ptr, esrc, thi, NNODES);
    mlp_kernel<true, true><<<mlp_grid, 128, 0, stream>>>(thi,
        wt_hi + 2 * 16384, wt_lo + 2 * 16384, wt_hi + 3 * 16384, wt_lo + 3 * 16384,
        p[12], p[13], p[14], p[15], p[16], p[18], p2h, batch, pooled, 128, NNODES);
    // layer 3 (no relu, no plane writes — pool-only output)
    agg_kernel<<<agg_grid, 256, 0, stream>>>(p2h, row_ptr, esrc, thi, NNODES);
    mlp_kernel<false, false><<<mlp_grid, 128, 0, stream>>>(thi,
        wt_hi + 4 * 16384, wt_lo + 4 * 16384, wt_hi + 5 * 16384, wt_lo + 5 * 16384,
        p[20], p[21], p[22], p[23], p[24], p[26], nullptr, batch, pooled, 256, NNODES);

    // --- final linear on mean-pooled JK-concat
    final_kernel<<<NGRAPHS, 128, 0, stream>>>(pooled, batch, lin_W, lin_b,
                                              (float*)d_out, NNODES);
}